// Round 1
// baseline (428.756 us; speedup 1.0000x reference)
//
#include <hip/hip_runtime.h>

#define H 2048
#define MDIM 512
#define NE 8
#define MS 1024
#define NTOK 2048
#define ACT_R_ROWS 5120

typedef unsigned short u16;
typedef __attribute__((ext_vector_type(8))) short s16x8;
typedef __attribute__((ext_vector_type(4))) float f32x4;

__device__ inline u16 f2bf(float f) {
  unsigned u = __builtin_bit_cast(unsigned, f);
  u = (u + 0x7fffu + ((u >> 16) & 1u)) >> 16;
  return (u16)u;
}

__device__ inline f32x4 mfma16(s16x8 a, s16x8 b, f32x4 c) {
  return __builtin_amdgcn_mfma_f32_16x16x32_bf16(a, b, c, 0, 0, 0);
}

// ---------------- utility kernels ----------------

__global__ void k_zero(int* counts) {
  if (threadIdx.x < NE) counts[threadIdx.x] = 0;
}

__global__ void k_cvt(const float* __restrict__ src, u16* __restrict__ dst, int n8) {
  int i = blockIdx.x * 256 + threadIdx.x;
  if (i >= n8) return;
  const f32x4* s = (const f32x4*)src;
  f32x4 a = s[2 * i + 0], b = s[2 * i + 1];
  s16x8 o;
  o[0] = (short)f2bf(a[0]); o[1] = (short)f2bf(a[1]);
  o[2] = (short)f2bf(a[2]); o[3] = (short)f2bf(a[3]);
  o[4] = (short)f2bf(b[0]); o[5] = (short)f2bf(b[1]);
  o[6] = (short)f2bf(b[2]); o[7] = (short)f2bf(b[3]);
  ((s16x8*)dst)[i] = o;
}

// transpose+convert: src fp32 [R][C] -> dst bf16 [C][R]; batch via blockIdx.z
__global__ void k_tcvt(const float* __restrict__ src, u16* __restrict__ dst,
                       int R, int C, long ss, long ds) {
  src += (long)blockIdx.z * ss;
  dst += (long)blockIdx.z * ds;
  __shared__ u16 t[32][33];
  int c0 = blockIdx.x * 32, r0 = blockIdx.y * 32;
  int tc = threadIdx.x & 31, tr = threadIdx.x >> 5;  // tr in [0,8)
  #pragma unroll
  for (int i = 0; i < 4; i++) {
    int rr = tr + i * 8;
    t[tc][rr] = f2bf(src[(long)(r0 + rr) * C + c0 + tc]);
  }
  __syncthreads();
  #pragma unroll
  for (int i = 0; i < 4; i++) {
    int rr = tr + i * 8;
    dst[(long)(c0 + rr) * R + r0 + tc] = t[rr][tc];
  }
}

// ---------------- router (fp64 logits, top-2 softmax) ----------------

__global__ void k_router(const float* __restrict__ x, const float* __restrict__ gw,
                         int* te, float* tw, int* slot, int* counts) {
  int n = blockIdx.x * 4 + (threadIdx.x >> 6);
  int lane = threadIdx.x & 63;
  double acc[NE];
  #pragma unroll
  for (int e = 0; e < NE; e++) acc[e] = 0.0;
  for (int j = lane; j < H; j += 64) {
    float xv = x[(long)n * H + j];
    #pragma unroll
    for (int e = 0; e < NE; e++) acc[e] += (double)xv * (double)gw[e * H + j];
  }
  #pragma unroll
  for (int off = 32; off; off >>= 1) {
    #pragma unroll
    for (int e = 0; e < NE; e++) acc[e] += __shfl_xor(acc[e], off);
  }
  if (lane == 0) {
    int b0 = 0; double v0 = acc[0];
    for (int e = 1; e < NE; e++) { if (acc[e] > v0) { v0 = acc[e]; b0 = e; } }
    int b1 = -1; double v1 = -1e300;
    for (int e = 0; e < NE; e++) { if (e != b0 && acc[e] > v1) { v1 = acc[e]; b1 = e; } }
    double ex = exp(v1 - v0);
    double w0 = 1.0 / (1.0 + ex);
    double w1 = ex / (1.0 + ex);
    te[n * 2] = b0; te[n * 2 + 1] = b1;
    tw[n * 2] = (float)w0; tw[n * 2 + 1] = (float)w1;
    slot[n * 2] = atomicAdd(&counts[b0], 1);
    slot[n * 2 + 1] = atomicAdd(&counts[b1], 1);
  }
}

__global__ void k_offsets(const int* counts, int* offs, int* perm) {
  if (threadIdx.x == 0) {
    int off = 0;
    for (int e = 0; e < NE; e++) { offs[e] = off; off += ((counts[e] + 127) >> 7) << 7; }
    offs[NE] = off;
  }
  for (int i = threadIdx.x; i < ACT_R_ROWS; i += blockDim.x) perm[i] = -1;
}

__global__ void k_scatter(const int* te, const float* tw, const int* slot,
                          const int* offs, int* perm, float* wgt) {
  int n = blockIdx.x * 256 + threadIdx.x;
  if (n >= NTOK) return;
  #pragma unroll
  for (int k = 0; k < 2; k++) {
    int e = te[n * 2 + k];
    int idx = offs[e] + slot[n * 2 + k];
    perm[idx] = n;
    wgt[idx] = tw[n * 2 + k];
  }
}

// ---------------- GEMM staging helper ----------------
// stage R rows x 32 k of bf16 into lds; src row stride = stride elems.
// GATHER: row index via permBase (absolute token row; -1 -> zeros).
template <int R, bool GATHER>
__device__ inline void stageTile(u16* lds, const u16* __restrict__ src, int stride, int k0,
                                 const int* __restrict__ permBase, int tid) {
  #pragma unroll
  for (int base = 0; base < R * 32; base += 2048) {
    int idx = base + tid * 8;
    int row = idx >> 5;
    int kof = idx & 31;
    s16x8 v = {0, 0, 0, 0, 0, 0, 0, 0};
    if (GATHER) {
      int srow = permBase[row];
      if (srow >= 0) v = *(const s16x8*)&src[(long)srow * stride + k0 + kof];
    } else {
      v = *(const s16x8*)&src[(long)row * stride + k0 + kof];
    }
    *(s16x8*)&lds[idx] = v;
  }
}

// ---------------- fused gate+up+SwiGLU GEMM ----------------
// C tile 128 rows x 64 cols; A = x (bf16 [*,H]); Bg/Bu = W^T (bf16 [Nout][H]).
// Writes act bf16 [rows][Nout].
template <bool GATHER>
__global__ __launch_bounds__(256) void k_gateup(
    const u16* __restrict__ xbf, const u16* __restrict__ BgT, const u16* __restrict__ BuT,
    u16* __restrict__ act, const int* __restrict__ perm, const int* __restrict__ counts,
    const int* __restrict__ offs, int Nout) {
  int bx = blockIdx.x, by = blockIdx.y, e = blockIdx.z;
  int cnt = NTOK, rowOff = 0;
  const int* permBase = nullptr;
  if (GATHER) {
    cnt = counts[e];
    if (bx * 128 >= cnt) return;
    rowOff = offs[e];
    permBase = perm + rowOff + bx * 128;
    BgT += (long)e * MDIM * H;
    BuT += (long)e * MDIM * H;
  }
  __shared__ u16 As[128 * 32];
  __shared__ u16 Bgs[64 * 32];
  __shared__ u16 Bus[64 * 32];
  int tid = threadIdx.x;
  int wave = tid >> 6, lane = tid & 63;
  int wr = wave >> 1, wc = wave & 1;
  int la = lane & 15, ks = lane >> 4;

  f32x4 zero4 = {0.f, 0.f, 0.f, 0.f};
  f32x4 gacc[4][2], uacc[4][2];
  #pragma unroll
  for (int m = 0; m < 4; m++)
    #pragma unroll
    for (int n = 0; n < 2; n++) { gacc[m][n] = zero4; uacc[m][n] = zero4; }

  const u16* Asrc = GATHER ? xbf : xbf + (long)bx * 128 * H;
  const u16* Bgsrc = BgT + (long)by * 64 * H;
  const u16* Busrc = BuT + (long)by * 64 * H;

  for (int k0 = 0; k0 < H; k0 += 32) {
    __syncthreads();
    stageTile<128, GATHER>(As, Asrc, H, k0, permBase, tid);
    stageTile<64, false>(Bgs, Bgsrc, H, k0, nullptr, tid);
    stageTile<64, false>(Bus, Busrc, H, k0, nullptr, tid);
    __syncthreads();
    s16x8 af[4], bg[2], bu[2];
    #pragma unroll
    for (int m = 0; m < 4; m++)
      af[m] = *(const s16x8*)&As[(wr * 64 + m * 16 + la) * 32 + ks * 8];
    #pragma unroll
    for (int n = 0; n < 2; n++) {
      bg[n] = *(const s16x8*)&Bgs[(wc * 32 + n * 16 + la) * 32 + ks * 8];
      bu[n] = *(const s16x8*)&Bus[(wc * 32 + n * 16 + la) * 32 + ks * 8];
    }
    #pragma unroll
    for (int m = 0; m < 4; m++) {
      #pragma unroll
      for (int n = 0; n < 2; n++) {
        gacc[m][n] = mfma16(af[m], bg[n], gacc[m][n]);
        uacc[m][n] = mfma16(af[m], bu[n], uacc[m][n]);
      }
    }
  }
  #pragma unroll
  for (int m = 0; m < 4; m++) {
    #pragma unroll
    for (int n = 0; n < 2; n++) {
      #pragma unroll
      for (int r = 0; r < 4; r++) {
        int lr = bx * 128 + wr * 64 + m * 16 + ks * 4 + r;
        int col = by * 64 + wc * 32 + n * 16 + la;
        float g = gacc[m][n][r], u = uacc[m][n][r];
        float a = (g / (1.0f + expf(-g))) * u;
        if (GATHER && lr >= cnt) a = 0.0f;
        act[(long)(rowOff + lr) * Nout + col] = f2bf(a);
      }
    }
  }
}

// ---------------- down GEMM ----------------
// C tile 128x128; A = act bf16 [rows][Kd]; BT = Wd^T bf16 [H][Kd].
// SCATTER: y[tok] += wgt * val (atomic); else y[row] = val.
template <bool SCATTER>
__global__ __launch_bounds__(256) void k_down(
    const u16* __restrict__ act, const u16* __restrict__ BT, float* __restrict__ y,
    const int* __restrict__ perm, const float* __restrict__ wgt,
    const int* __restrict__ counts, const int* __restrict__ offs, int Kd) {
  int bx = blockIdx.x, by = blockIdx.y, e = blockIdx.z;
  int cnt = NTOK, rowOff = 0;
  if (SCATTER) {
    cnt = counts[e];
    if (bx * 128 >= cnt) return;
    rowOff = offs[e];
    BT += (long)e * H * MDIM;
  }
  __shared__ u16 As[128 * 32];
  __shared__ u16 Bs[128 * 32];
  int tid = threadIdx.x;
  int wave = tid >> 6, lane = tid & 63;
  int wr = wave >> 1, wc = wave & 1;
  int la = lane & 15, ks = lane >> 4;
  f32x4 zero4 = {0.f, 0.f, 0.f, 0.f};
  f32x4 acc[4][4];
  #pragma unroll
  for (int m = 0; m < 4; m++)
    #pragma unroll
    for (int n = 0; n < 4; n++) acc[m][n] = zero4;

  const u16* Asrc = act + (long)(rowOff + bx * 128) * Kd;
  const u16* Bsrc = BT + (long)by * 128 * Kd;

  for (int k0 = 0; k0 < Kd; k0 += 32) {
    __syncthreads();
    stageTile<128, false>(As, Asrc, Kd, k0, nullptr, tid);
    stageTile<128, false>(Bs, Bsrc, Kd, k0, nullptr, tid);
    __syncthreads();
    s16x8 af[4], bfr[4];
    #pragma unroll
    for (int m = 0; m < 4; m++)
      af[m] = *(const s16x8*)&As[(wr * 64 + m * 16 + la) * 32 + ks * 8];
    #pragma unroll
    for (int n = 0; n < 4; n++)
      bfr[n] = *(const s16x8*)&Bs[(wc * 64 + n * 16 + la) * 32 + ks * 8];
    #pragma unroll
    for (int m = 0; m < 4; m++)
      #pragma unroll
      for (int n = 0; n < 4; n++) acc[m][n] = mfma16(af[m], bfr[n], acc[m][n]);
  }
  #pragma unroll
  for (int m = 0; m < 4; m++) {
    #pragma unroll
    for (int n = 0; n < 4; n++) {
      #pragma unroll
      for (int r = 0; r < 4; r++) {
        int lr = bx * 128 + wr * 64 + m * 16 + ks * 4 + r;
        int col = by * 128 + wc * 64 + n * 16 + la;
        float v = acc[m][n][r];
        if (SCATTER) {
          if (lr < cnt) {
            int si = rowOff + lr;
            int tok = perm[si];
            atomicAdd(&y[(long)tok * H + col], wgt[si] * v);
          }
        } else {
          y[(long)lr * H + col] = v;
        }
      }
    }
  }
}

// ---------------- host launch ----------------

extern "C" void kernel_launch(void* const* d_in, const int* in_sizes, int n_in,
                              void* d_out, int out_size, void* d_ws, size_t ws_size,
                              hipStream_t stream) {
  const float* x   = (const float*)d_in[0];
  const float* gw  = (const float*)d_in[1];
  const float* Wg  = (const float*)d_in[2];
  const float* Wu  = (const float*)d_in[3];
  const float* Wd  = (const float*)d_in[4];
  const float* sWg = (const float*)d_in[5];
  const float* sWu = (const float*)d_in[6];
  const float* sWd = (const float*)d_in[7];
  float* y = (float*)d_out;

  char* w = (char*)d_ws;
  auto alloc = [&](size_t bytes) {
    char* p = w;
    w += (bytes + 255) & ~(size_t)255;
    return p;
  };
  u16* xbf   = (u16*)alloc((size_t)NTOK * H * 2);
  u16* WgT   = (u16*)alloc((size_t)NE * MDIM * H * 2);
  u16* WuT   = (u16*)alloc((size_t)NE * MDIM * H * 2);
  u16* WdT   = (u16*)alloc((size_t)NE * H * MDIM * 2);
  u16* sWgT  = (u16*)alloc((size_t)MS * H * 2);
  u16* sWuT  = (u16*)alloc((size_t)MS * H * 2);
  u16* sWdT  = (u16*)alloc((size_t)H * MS * 2);
  u16* act_s = (u16*)alloc((size_t)NTOK * MS * 2);
  u16* act_r = (u16*)alloc((size_t)ACT_R_ROWS * MDIM * 2);
  int*   te     = (int*)alloc((size_t)NTOK * 2 * 4);
  float* tw     = (float*)alloc((size_t)NTOK * 2 * 4);
  int*   slot   = (int*)alloc((size_t)NTOK * 2 * 4);
  int*   counts = (int*)alloc(64);
  int*   offs   = (int*)alloc(64);
  int*   perm   = (int*)alloc((size_t)ACT_R_ROWS * 4);
  float* wgt    = (float*)alloc((size_t)ACT_R_ROWS * 4);

  k_zero<<<1, 64, 0, stream>>>(counts);

  int n8 = NTOK * H / 8;
  k_cvt<<<(n8 + 255) / 256, 256, 0, stream>>>(x, xbf, n8);
  k_tcvt<<<dim3(MDIM / 32, H / 32, NE), 256, 0, stream>>>(Wg, WgT, H, MDIM, (long)H * MDIM, (long)MDIM * H);
  k_tcvt<<<dim3(MDIM / 32, H / 32, NE), 256, 0, stream>>>(Wu, WuT, H, MDIM, (long)H * MDIM, (long)MDIM * H);
  k_tcvt<<<dim3(H / 32, MDIM / 32, NE), 256, 0, stream>>>(Wd, WdT, MDIM, H, (long)MDIM * H, (long)H * MDIM);
  k_tcvt<<<dim3(MS / 32, H / 32, 1), 256, 0, stream>>>(sWg, sWgT, H, MS, 0, 0);
  k_tcvt<<<dim3(MS / 32, H / 32, 1), 256, 0, stream>>>(sWu, sWuT, H, MS, 0, 0);
  k_tcvt<<<dim3(H / 32, MS / 32, 1), 256, 0, stream>>>(sWd, sWdT, MS, H, 0, 0);

  k_router<<<NTOK / 4, 256, 0, stream>>>(x, gw, te, tw, slot, counts);
  k_offsets<<<1, 256, 0, stream>>>(counts, offs, perm);
  k_scatter<<<NTOK / 256, 256, 0, stream>>>(te, tw, slot, offs, perm, wgt);

  // shared gate/up: 2048 x 1024, col tile 64
  k_gateup<false><<<dim3(NTOK / 128, MS / 64, 1), 256, 0, stream>>>(
      xbf, sWgT, sWuT, act_s, nullptr, nullptr, nullptr, MS);
  // routed gate/up: per-expert, gathered rows
  k_gateup<true><<<dim3(NTOK / 128, MDIM / 64, NE), 256, 0, stream>>>(
      xbf, WgT, WuT, act_r, perm, counts, offs, MDIM);
  // shared down: writes y densely (must precede routed scatter)
  k_down<false><<<dim3(NTOK / 128, H / 128, 1), 256, 0, stream>>>(
      act_s, sWdT, y, nullptr, nullptr, nullptr, nullptr, MS);
  // routed down: atomic weighted scatter into y
  k_down<true><<<dim3(NTOK / 128, H / 128, NE), 256, 0, stream>>>(
      act_r, WdT, y, perm, wgt, counts, offs, MDIM);
}

// Round 2
// 315.138 us; speedup vs baseline: 1.3605x; 1.3605x over previous
//
#include <hip/hip_runtime.h>

#define H 2048
#define MDIM 512
#define NE 8
#define MS 1024
#define NTOK 2048
#define ACT_R_ROWS 5120

typedef unsigned short u16;
typedef __attribute__((ext_vector_type(8))) short s16x8;
typedef __attribute__((ext_vector_type(4))) float f32x4;

__device__ inline u16 f2bf(float f) {
  unsigned u = __builtin_bit_cast(unsigned, f);
  u = (u + 0x7fffu + ((u >> 16) & 1u)) >> 16;
  return (u16)u;
}

__device__ inline f32x4 mfma16(s16x8 a, s16x8 b, f32x4 c) {
  return __builtin_amdgcn_mfma_f32_16x16x32_bf16(a, b, c, 0, 0, 0);
}

// async global->LDS, 16B per lane. LDS dest must be wave-uniform base (+lane*16).
__device__ inline void gload16(const void* g, void* l) {
  __builtin_amdgcn_global_load_lds(
      (const __attribute__((address_space(1))) unsigned int*)g,
      (__attribute__((address_space(3))) unsigned int*)l, 16, 0, 0);
}

// ---------------- utility kernels ----------------

__global__ void k_zero(int* counts) {
  if (threadIdx.x < NE) counts[threadIdx.x] = 0;
}

__global__ void k_cvt(const float* __restrict__ src, u16* __restrict__ dst, int n8) {
  int i = blockIdx.x * 256 + threadIdx.x;
  if (i >= n8) return;
  const f32x4* s = (const f32x4*)src;
  f32x4 a = s[2 * i + 0], b = s[2 * i + 1];
  s16x8 o;
  o[0] = (short)f2bf(a[0]); o[1] = (short)f2bf(a[1]);
  o[2] = (short)f2bf(a[2]); o[3] = (short)f2bf(a[3]);
  o[4] = (short)f2bf(b[0]); o[5] = (short)f2bf(b[1]);
  o[6] = (short)f2bf(b[2]); o[7] = (short)f2bf(b[3]);
  ((s16x8*)dst)[i] = o;
}

// transpose+convert: src fp32 [R][C] -> dst bf16 [C][R]; batch via blockIdx.z
__global__ void k_tcvt(const float* __restrict__ src, u16* __restrict__ dst,
                       int R, int C, long ss, long ds) {
  src += (long)blockIdx.z * ss;
  dst += (long)blockIdx.z * ds;
  __shared__ u16 t[32][33];
  int c0 = blockIdx.x * 32, r0 = blockIdx.y * 32;
  int tc = threadIdx.x & 31, tr = threadIdx.x >> 5;  // tr in [0,8)
  #pragma unroll
  for (int i = 0; i < 4; i++) {
    int rr = tr + i * 8;
    t[tc][rr] = f2bf(src[(long)(r0 + rr) * C + c0 + tc]);
  }
  __syncthreads();
  #pragma unroll
  for (int i = 0; i < 4; i++) {
    int rr = tr + i * 8;
    dst[(long)(c0 + rr) * R + r0 + tc] = t[rr][tc];
  }
}

// ---------------- router (fp64 logits, top-2 softmax) ----------------

__global__ void k_router(const float* __restrict__ x, const float* __restrict__ gw,
                         int* te, float* tw, int* slot, int* counts) {
  int n = blockIdx.x * 4 + (threadIdx.x >> 6);
  int lane = threadIdx.x & 63;
  double acc[NE];
  #pragma unroll
  for (int e = 0; e < NE; e++) acc[e] = 0.0;
  for (int j = lane; j < H; j += 64) {
    float xv = x[(long)n * H + j];
    #pragma unroll
    for (int e = 0; e < NE; e++) acc[e] += (double)xv * (double)gw[e * H + j];
  }
  #pragma unroll
  for (int off = 32; off; off >>= 1) {
    #pragma unroll
    for (int e = 0; e < NE; e++) acc[e] += __shfl_xor(acc[e], off);
  }
  if (lane == 0) {
    int b0 = 0; double v0 = acc[0];
    for (int e = 1; e < NE; e++) { if (acc[e] > v0) { v0 = acc[e]; b0 = e; } }
    int b1 = -1; double v1 = -1e300;
    for (int e = 0; e < NE; e++) { if (e != b0 && acc[e] > v1) { v1 = acc[e]; b1 = e; } }
    double ex = exp(v1 - v0);
    double w0 = 1.0 / (1.0 + ex);
    double w1 = ex / (1.0 + ex);
    te[n * 2] = b0; te[n * 2 + 1] = b1;
    tw[n * 2] = (float)w0; tw[n * 2 + 1] = (float)w1;
    slot[n * 2] = atomicAdd(&counts[b0], 1);
    slot[n * 2 + 1] = atomicAdd(&counts[b1], 1);
  }
}

__global__ void k_offsets(const int* counts, int* offs, int* perm) {
  if (threadIdx.x == 0) {
    int off = 0;
    for (int e = 0; e < NE; e++) { offs[e] = off; off += ((counts[e] + 127) >> 7) << 7; }
    offs[NE] = off;
  }
  for (int i = threadIdx.x; i < ACT_R_ROWS; i += blockDim.x) perm[i] = 0;  // safe default row
}

__global__ void k_scatter(const int* te, const float* tw, const int* slot,
                          const int* offs, int* perm, float* wgt) {
  int n = blockIdx.x * 256 + threadIdx.x;
  if (n >= NTOK) return;
  #pragma unroll
  for (int k = 0; k < 2; k++) {
    int e = te[n * 2 + k];
    int idx = offs[e] + slot[n * 2 + k];
    perm[idx] = n;
    wgt[idx] = tw[n * 2 + k];
  }
}

// ---------------- fused gate+up+SwiGLU GEMM (m97 structure) ----------------
// C tile 128 rows x 128 cols; A = x bf16 [*,H]; Bg/Bu = W^T bf16 [Nout][H].
// z=0: shared expert (dense rows). z>=1: routed expert e=z-1, gathered rows.
// LDS tiles [128 rows][64 k] bf16 = 128B rows, XOR-swizzled via pre-swizzled
// global source (linear LDS dest for global_load_lds), swizzled ds_read.
__global__ __launch_bounds__(256, 2) void k_gu(
    const u16* __restrict__ xbf, const u16* __restrict__ WgT, const u16* __restrict__ WuT,
    const u16* __restrict__ sWgT, const u16* __restrict__ sWuT,
    u16* __restrict__ act_s, u16* __restrict__ act_r,
    const int* __restrict__ perm, const int* __restrict__ counts,
    const int* __restrict__ offs) {
  int bx = blockIdx.x, by = blockIdx.y, z = blockIdx.z;
  const u16 *Bg, *Bu;
  u16* act;
  int Nout, cnt, rowBase;
  bool gather = (z > 0);
  if (gather) {
    int e = z - 1;
    if (by >= MDIM / 128) return;
    cnt = counts[e];
    if (bx * 128 >= cnt) return;
    rowBase = offs[e] + bx * 128;
    Bg = WgT + ((size_t)e * MDIM + (size_t)by * 128) * H;
    Bu = WuT + ((size_t)e * MDIM + (size_t)by * 128) * H;
    act = act_r; Nout = MDIM;
  } else {
    cnt = NTOK; rowBase = bx * 128;
    Bg = sWgT + (size_t)by * 128 * H;
    Bu = sWuT + (size_t)by * 128 * H;
    act = act_s; Nout = MS;
  }

  __shared__ u16 As[128 * 64];
  __shared__ u16 Bgs[128 * 64];
  __shared__ u16 Bus[128 * 64];

  int tid = threadIdx.x;
  int wave = tid >> 6, lane = tid & 63;
  int wr = wave >> 1, wc = wave & 1;
  int la = lane & 15, ks = lane >> 4;

  // --- staging source addresses (pre-swizzled columns, rule #21) ---
  int rIn = tid >> 3;                                   // 0..31: row within 32-row stripe
  int csrc = ((tid & 7) << 4) ^ ((rIn & 7) << 4);       // swizzled 16B chunk within 128B row
  const char* srcA[4];
  const char* srcBg[4];
  const char* srcBu[4];
  #pragma unroll
  for (int j = 0; j < 4; j++) {
    int row = j * 32 + rIn;                             // row within 128-row tile
    int arow = gather ? perm[rowBase + row] : (rowBase + row);  // absolute token row
    srcA[j]  = (const char*)xbf + (size_t)arow * H * 2 + csrc;
    srcBg[j] = (const char*)Bg + (size_t)row * H * 2 + csrc;
    srcBu[j] = (const char*)Bu + (size_t)row * H * 2 + csrc;
  }

  // --- fragment read offsets (swizzled) ---
  int xr = (la & 7) << 4;
  int offA[4][2], offB[4][2];
  #pragma unroll
  for (int m = 0; m < 4; m++) {
    int arow = wr * 64 + m * 16 + la;
    int brow = wc * 64 + m * 16 + la;
    #pragma unroll
    for (int kk = 0; kk < 2; kk++) {
      int c = kk * 64 + ks * 16;
      offA[m][kk] = arow * 128 + (c ^ xr);
      offB[m][kk] = brow * 128 + (c ^ xr);
    }
  }

  f32x4 zero4 = {0.f, 0.f, 0.f, 0.f};
  f32x4 gacc[4][4], uacc[4][4];
  #pragma unroll
  for (int m = 0; m < 4; m++)
    #pragma unroll
    for (int n = 0; n < 4; n++) { gacc[m][n] = zero4; uacc[m][n] = zero4; }

  for (int k0 = 0; k0 < H * 2; k0 += 128) {  // byte offset along K
    __syncthreads();
    #pragma unroll
    for (int j = 0; j < 4; j++) {
      char* ldsoff = (char*)nullptr + (size_t)(j * 4096 + wave * 1024);
      gload16(srcA[j] + k0, (char*)As + (j * 4096 + wave * 1024));
      gload16(srcBg[j] + k0, (char*)Bgs + (j * 4096 + wave * 1024));
      gload16(srcBu[j] + k0, (char*)Bus + (j * 4096 + wave * 1024));
      (void)ldsoff;
    }
    __syncthreads();
    #pragma unroll
    for (int kk = 0; kk < 2; kk++) {
      s16x8 a[4], g[4], u[4];
      #pragma unroll
      for (int m = 0; m < 4; m++) a[m] = *(const s16x8*)((const char*)As + offA[m][kk]);
      #pragma unroll
      for (int n = 0; n < 4; n++) {
        g[n] = *(const s16x8*)((const char*)Bgs + offB[n][kk]);
        u[n] = *(const s16x8*)((const char*)Bus + offB[n][kk]);
      }
      #pragma unroll
      for (int m = 0; m < 4; m++) {
        #pragma unroll
        for (int n = 0; n < 4; n++) {
          gacc[m][n] = mfma16(a[m], g[n], gacc[m][n]);
          uacc[m][n] = mfma16(a[m], u[n], uacc[m][n]);
        }
      }
    }
  }

  #pragma unroll
  for (int m = 0; m < 4; m++) {
    #pragma unroll
    for (int n = 0; n < 4; n++) {
      #pragma unroll
      for (int r = 0; r < 4; r++) {
        int lr = wr * 64 + m * 16 + ks * 4 + r;     // local row 0..127
        int col = by * 128 + wc * 64 + n * 16 + la;
        float g = gacc[m][n][r], u = uacc[m][n][r];
        float a = g / (1.0f + __expf(-g)) * u;
        if (gather && (bx * 128 + lr) >= cnt) a = 0.0f;
        act[(size_t)(rowBase + lr) * Nout + col] = f2bf(a);
      }
    }
  }
}

// ---------------- down GEMM (m97 structure) ----------------
// C tile 128x128; A = act bf16 [rows][Kd]; BT = Wd^T bf16 [H][Kd].
template <bool SCATTER>
__global__ __launch_bounds__(256, 2) void k_down(
    const u16* __restrict__ act, const u16* __restrict__ BT, float* __restrict__ y,
    const int* __restrict__ perm, const float* __restrict__ wgt,
    const int* __restrict__ counts, const int* __restrict__ offs, int Kd) {
  int bx = blockIdx.x, by = blockIdx.y, e = blockIdx.z;
  int cnt = NTOK, rowBase = bx * 128;
  const u16* B = BT;
  if (SCATTER) {
    cnt = counts[e];
    if (bx * 128 >= cnt) return;
    rowBase = offs[e] + bx * 128;
    B = BT + (size_t)e * H * MDIM;
  }
  B += (size_t)by * 128 * Kd;

  __shared__ u16 As[128 * 64];
  __shared__ u16 Bs[128 * 64];

  int tid = threadIdx.x;
  int wave = tid >> 6, lane = tid & 63;
  int wr = wave >> 1, wc = wave & 1;
  int la = lane & 15, ks = lane >> 4;

  int rIn = tid >> 3;
  int csrc = ((tid & 7) << 4) ^ ((rIn & 7) << 4);
  const char* srcA[4];
  const char* srcB[4];
  #pragma unroll
  for (int j = 0; j < 4; j++) {
    int row = j * 32 + rIn;
    srcA[j] = (const char*)act + ((size_t)(rowBase + row) * Kd) * 2 + csrc;
    srcB[j] = (const char*)B + ((size_t)row * Kd) * 2 + csrc;
  }

  int xr = (la & 7) << 4;
  int offA[4][2], offB[4][2];
  #pragma unroll
  for (int m = 0; m < 4; m++) {
    int arow = wr * 64 + m * 16 + la;
    int brow = wc * 64 + m * 16 + la;
    #pragma unroll
    for (int kk = 0; kk < 2; kk++) {
      int c = kk * 64 + ks * 16;
      offA[m][kk] = arow * 128 + (c ^ xr);
      offB[m][kk] = brow * 128 + (c ^ xr);
    }
  }

  f32x4 zero4 = {0.f, 0.f, 0.f, 0.f};
  f32x4 acc[4][4];
  #pragma unroll
  for (int m = 0; m < 4; m++)
    #pragma unroll
    for (int n = 0; n < 4; n++) acc[m][n] = zero4;

  for (int k0 = 0; k0 < Kd * 2; k0 += 128) {
    __syncthreads();
    #pragma unroll
    for (int j = 0; j < 4; j++) {
      gload16(srcA[j] + k0, (char*)As + (j * 4096 + wave * 1024));
      gload16(srcB[j] + k0, (char*)Bs + (j * 4096 + wave * 1024));
    }
    __syncthreads();
    #pragma unroll
    for (int kk = 0; kk < 2; kk++) {
      s16x8 a[4], b[4];
      #pragma unroll
      for (int m = 0; m < 4; m++) a[m] = *(const s16x8*)((const char*)As + offA[m][kk]);
      #pragma unroll
      for (int n = 0; n < 4; n++) b[n] = *(const s16x8*)((const char*)Bs + offB[n][kk]);
      #pragma unroll
      for (int m = 0; m < 4; m++)
        #pragma unroll
        for (int n = 0; n < 4; n++) acc[m][n] = mfma16(a[m], b[n], acc[m][n]);
    }
  }

  #pragma unroll
  for (int m = 0; m < 4; m++) {
    #pragma unroll
    for (int n = 0; n < 4; n++) {
      #pragma unroll
      for (int r = 0; r < 4; r++) {
        int lr = wr * 64 + m * 16 + ks * 4 + r;
        int col = by * 128 + wc * 64 + n * 16 + la;
        float v = acc[m][n][r];
        if (SCATTER) {
          if (bx * 128 + lr < cnt) {
            int si = rowBase + lr;
            atomicAdd(&y[(size_t)perm[si] * H + col], wgt[si] * v);
          }
        } else {
          y[(size_t)(bx * 128 + lr) * H + col] = v;
        }
      }
    }
  }
}

// ---------------- host launch ----------------

extern "C" void kernel_launch(void* const* d_in, const int* in_sizes, int n_in,
                              void* d_out, int out_size, void* d_ws, size_t ws_size,
                              hipStream_t stream) {
  const float* x   = (const float*)d_in[0];
  const float* gw  = (const float*)d_in[1];
  const float* Wg  = (const float*)d_in[2];
  const float* Wu  = (const float*)d_in[3];
  const float* Wd  = (const float*)d_in[4];
  const float* sWg = (const float*)d_in[5];
  const float* sWu = (const float*)d_in[6];
  const float* sWd = (const float*)d_in[7];
  float* y = (float*)d_out;

  char* w = (char*)d_ws;
  auto alloc = [&](size_t bytes) {
    char* p = w;
    w += (bytes + 255) & ~(size_t)255;
    return p;
  };
  u16* xbf   = (u16*)alloc((size_t)NTOK * H * 2);
  u16* WgT   = (u16*)alloc((size_t)NE * MDIM * H * 2);
  u16* WuT   = (u16*)alloc((size_t)NE * MDIM * H * 2);
  u16* WdT   = (u16*)alloc((size_t)NE * H * MDIM * 2);
  u16* sWgT  = (u16*)alloc((size_t)MS * H * 2);
  u16* sWuT  = (u16*)alloc((size_t)MS * H * 2);
  u16* sWdT  = (u16*)alloc((size_t)H * MS * 2);
  u16* act_s = (u16*)alloc((size_t)NTOK * MS * 2);
  u16* act_r = (u16*)alloc((size_t)ACT_R_ROWS * MDIM * 2);
  int*   te     = (int*)alloc((size_t)NTOK * 2 * 4);
  float* tw     = (float*)alloc((size_t)NTOK * 2 * 4);
  int*   slot   = (int*)alloc((size_t)NTOK * 2 * 4);
  int*   counts = (int*)alloc(64);
  int*   offs   = (int*)alloc(64);
  int*   perm   = (int*)alloc((size_t)ACT_R_ROWS * 4);
  float* wgt    = (float*)alloc((size_t)ACT_R_ROWS * 4);

  k_zero<<<1, 64, 0, stream>>>(counts);

  int n8 = NTOK * H / 8;
  k_cvt<<<(n8 + 255) / 256, 256, 0, stream>>>(x, xbf, n8);
  k_tcvt<<<dim3(MDIM / 32, H / 32, NE), 256, 0, stream>>>(Wg, WgT, H, MDIM, (long)H * MDIM, (long)MDIM * H);
  k_tcvt<<<dim3(MDIM / 32, H / 32, NE), 256, 0, stream>>>(Wu, WuT, H, MDIM, (long)H * MDIM, (long)MDIM * H);
  k_tcvt<<<dim3(H / 32, MDIM / 32, NE), 256, 0, stream>>>(Wd, WdT, MDIM, H, (long)MDIM * H, (long)H * MDIM);
  k_tcvt<<<dim3(MS / 32, H / 32, 1), 256, 0, stream>>>(sWg, sWgT, H, MS, 0, 0);
  k_tcvt<<<dim3(MS / 32, H / 32, 1), 256, 0, stream>>>(sWu, sWuT, H, MS, 0, 0);
  k_tcvt<<<dim3(H / 32, MS / 32, 1), 256, 0, stream>>>(sWd, sWdT, MS, H, 0, 0);

  k_router<<<NTOK / 4, 256, 0, stream>>>(x, gw, te, tw, slot, counts);
  k_offsets<<<1, 256, 0, stream>>>(counts, offs, perm);
  k_scatter<<<NTOK / 256, 256, 0, stream>>>(te, tw, slot, offs, perm, wgt);

  // merged shared (z=0) + routed (z=1..8) gate/up, fused SwiGLU
  k_gu<<<dim3(NTOK / 128, MS / 128, 1 + NE), 256, 0, stream>>>(
      xbf, WgT, WuT, sWgT, sWuT, act_s, act_r, perm, counts, offs);

  // shared down: dense write into y (must precede routed scatter)
  k_down<false><<<dim3(NTOK / 128, H / 128, 1), 256, 0, stream>>>(
      act_s, sWdT, y, nullptr, nullptr, nullptr, nullptr, MS);
  // routed down: atomic weighted scatter into y
  k_down<true><<<dim3(NTOK / 128, H / 128, NE), 256, 0, stream>>>(
      act_r, WdT, y, perm, wgt, counts, offs, MDIM);
}

// Round 3
// 271.007 us; speedup vs baseline: 1.5821x; 1.1628x over previous
//
#include <hip/hip_runtime.h>

#define H 2048
#define MDIM 512
#define NE 8
#define MS 1024
#define NTOK 2048
#define ACT_R_ROWS 5120

typedef unsigned short u16;
typedef __attribute__((ext_vector_type(8))) short s16x8;
typedef __attribute__((ext_vector_type(4))) float f32x4;

__device__ inline u16 f2bf(float f) {
  unsigned u = __builtin_bit_cast(unsigned, f);
  u = (u + 0x7fffu + ((u >> 16) & 1u)) >> 16;
  return (u16)u;
}

__device__ inline f32x4 mfma16(s16x8 a, s16x8 b, f32x4 c) {
  return __builtin_amdgcn_mfma_f32_16x16x32_bf16(a, b, c, 0, 0, 0);
}

// async global->LDS, 16B per lane. LDS dest wave-uniform base (+lane*16).
__device__ inline void gload16(const void* g, void* l) {
  __builtin_amdgcn_global_load_lds(
      (const __attribute__((address_space(1))) unsigned int*)g,
      (__attribute__((address_space(3))) unsigned int*)l, 16, 0, 0);
}

__device__ inline void pipe_fence() {
  __builtin_amdgcn_sched_barrier(0);
  asm volatile("s_waitcnt vmcnt(0)" ::: "memory");
  __builtin_amdgcn_s_barrier();
}

// ---------------- utility kernels ----------------

__global__ void k_zero(int* counts) {
  if (threadIdx.x < NE) counts[threadIdx.x] = 0;
}

__global__ void k_cvt(const float* __restrict__ src, u16* __restrict__ dst, int n8) {
  int i = blockIdx.x * 256 + threadIdx.x;
  if (i >= n8) return;
  const f32x4* s = (const f32x4*)src;
  f32x4 a = s[2 * i + 0], b = s[2 * i + 1];
  s16x8 o;
  o[0] = (short)f2bf(a[0]); o[1] = (short)f2bf(a[1]);
  o[2] = (short)f2bf(a[2]); o[3] = (short)f2bf(a[3]);
  o[4] = (short)f2bf(b[0]); o[5] = (short)f2bf(b[1]);
  o[6] = (short)f2bf(b[2]); o[7] = (short)f2bf(b[3]);
  ((s16x8*)dst)[i] = o;
}

// vectorized transpose+convert: src fp32 [R][C] -> dst bf16 [C][R], 64x64 tiles
__global__ __launch_bounds__(256) void k_t64(const float* __restrict__ src,
                                             u16* __restrict__ dst,
                                             int R, int C, long ss, long ds) {
  src += (long)blockIdx.z * ss;
  dst += (long)blockIdx.z * ds;
  __shared__ u16 tt[64][66];
  int c0 = blockIdx.x * 64, r0 = blockIdx.y * 64;
  int t = threadIdx.x;
  int cq = (t & 15) * 4, rr = t >> 4;
  #pragma unroll
  for (int i = 0; i < 4; i++) {
    int row = rr + i * 16;
    f32x4 v = *(const f32x4*)&src[(long)(r0 + row) * C + c0 + cq];
    tt[cq + 0][row] = f2bf(v[0]);
    tt[cq + 1][row] = f2bf(v[1]);
    tt[cq + 2][row] = f2bf(v[2]);
    tt[cq + 3][row] = f2bf(v[3]);
  }
  __syncthreads();
  int c = t >> 2, ch = t & 3;
  #pragma unroll
  for (int h = 0; h < 2; h++) {
    int chunk = ch + h * 4;
    const u16* p = &tt[c][chunk * 8];
    s16x8 o;
    #pragma unroll
    for (int w0 = 0; w0 < 8; w0++) o[w0] = (short)p[w0];
    *(s16x8*)&dst[(long)(c0 + c) * R + r0 + chunk * 8] = o;
  }
}

// ---------------- router (fp64 logits, top-2 softmax) ----------------

__global__ void k_router(const float* __restrict__ x, const float* __restrict__ gw,
                         int* te, float* tw, int* slot, int* counts) {
  int n = blockIdx.x * 4 + (threadIdx.x >> 6);
  int lane = threadIdx.x & 63;
  double acc[NE];
  #pragma unroll
  for (int e = 0; e < NE; e++) acc[e] = 0.0;
  for (int j = lane; j < H; j += 64) {
    float xv = x[(long)n * H + j];
    #pragma unroll
    for (int e = 0; e < NE; e++) acc[e] += (double)xv * (double)gw[e * H + j];
  }
  #pragma unroll
  for (int off = 32; off; off >>= 1) {
    #pragma unroll
    for (int e = 0; e < NE; e++) acc[e] += __shfl_xor(acc[e], off);
  }
  if (lane == 0) {
    int b0 = 0; double v0 = acc[0];
    for (int e = 1; e < NE; e++) { if (acc[e] > v0) { v0 = acc[e]; b0 = e; } }
    int b1 = -1; double v1 = -1e300;
    for (int e = 0; e < NE; e++) { if (e != b0 && acc[e] > v1) { v1 = acc[e]; b1 = e; } }
    double ex = exp(v1 - v0);
    te[n * 2] = b0; te[n * 2 + 1] = b1;
    tw[n * 2] = (float)(1.0 / (1.0 + ex));
    tw[n * 2 + 1] = (float)(ex / (1.0 + ex));
    slot[n * 2] = atomicAdd(&counts[b0], 1);
    slot[n * 2 + 1] = atomicAdd(&counts[b1], 1);
  }
}

__global__ void k_offsets(const int* counts, int* offs, int* perm) {
  if (threadIdx.x == 0) {
    int off = 0;
    for (int e = 0; e < NE; e++) { offs[e] = off; off += ((counts[e] + 127) >> 7) << 7; }
    offs[NE] = off;
  }
  for (int i = threadIdx.x; i < ACT_R_ROWS; i += blockDim.x) perm[i] = 0;
}

__global__ void k_scatter(const int* te, const float* tw, const int* slot,
                          const int* offs, int* perm, float* wgt) {
  int n = blockIdx.x * 256 + threadIdx.x;
  if (n >= NTOK) return;
  #pragma unroll
  for (int k = 0; k < 2; k++) {
    int e = te[n * 2 + k];
    int idx = offs[e] + slot[n * 2 + k];
    perm[idx] = n;
    wgt[idx] = tw[n * 2 + k];
  }
}

// ---------------- fused gate+up+SwiGLU GEMM, 2-phase prefetch ----------------
// C tile 128 rows x 64 cols. z=0: shared expert; z>=1: routed expert z-1.
// LDS buffer: A[128][64] (16KB) + Bg[64][64] (8KB) + Bu[64][64] (8KB) = 32KB, x2.
__global__ __launch_bounds__(256, 2) void k_gu(
    const u16* __restrict__ xbf, const u16* __restrict__ WgT, const u16* __restrict__ WuT,
    const u16* __restrict__ sWgT, const u16* __restrict__ sWuT,
    u16* __restrict__ act_s, u16* __restrict__ act_r,
    const int* __restrict__ perm, const int* __restrict__ counts,
    const int* __restrict__ offs) {
  int bx = blockIdx.x, by = blockIdx.y, z = blockIdx.z;
  const u16 *Bg, *Bu;
  u16* act;
  int Nout, cnt, rowBase;
  bool gather = (z > 0);
  if (gather) {
    int e = z - 1;
    if (by >= MDIM / 64) return;
    cnt = counts[e];
    if (bx * 128 >= cnt) return;
    rowBase = offs[e] + bx * 128;
    Bg = WgT + ((size_t)e * MDIM + (size_t)by * 64) * H;
    Bu = WuT + ((size_t)e * MDIM + (size_t)by * 64) * H;
    act = act_r; Nout = MDIM;
  } else {
    cnt = NTOK; rowBase = bx * 128;
    Bg = sWgT + (size_t)by * 64 * H;
    Bu = sWuT + (size_t)by * 64 * H;
    act = act_s; Nout = MS;
  }

  __shared__ char lds[2][32768];  // A:0..16K, Bg:16K..24K, Bu:24K..32K

  int tid = threadIdx.x;
  int wave = tid >> 6, lane = tid & 63;
  int wr = wave >> 1, wc = wave & 1;
  int la = lane & 15, ks = lane >> 4;

  // staging sources (pre-swizzled chunk; rule #21 both-sides)
  int rIn = tid >> 3;
  int csrc = ((tid & 7) << 4) ^ ((rIn & 7) << 4);
  const char* srcA[4];
  const char* srcBg[2];
  const char* srcBu[2];
  #pragma unroll
  for (int j = 0; j < 4; j++) {
    int row = j * 32 + rIn;
    int tok = gather ? perm[rowBase + row] : (rowBase + row);
    srcA[j] = (const char*)xbf + (size_t)tok * H * 2 + csrc;
  }
  #pragma unroll
  for (int j = 0; j < 2; j++) {
    int row = j * 32 + rIn;
    srcBg[j] = (const char*)Bg + (size_t)row * H * 2 + csrc;
    srcBu[j] = (const char*)Bu + (size_t)row * H * 2 + csrc;
  }

  // fragment read offsets (swizzled), relative to buffer base
  int offA[4][2], offB[2][2];
  #pragma unroll
  for (int m = 0; m < 4; m++) {
    int arow = wr * 64 + m * 16 + la;
    #pragma unroll
    for (int kk = 0; kk < 2; kk++) {
      int c = kk * 64 + ks * 16;
      offA[m][kk] = arow * 128 + (c ^ ((arow & 7) << 4));
    }
  }
  #pragma unroll
  for (int n = 0; n < 2; n++) {
    int brow = wc * 32 + n * 16 + la;
    #pragma unroll
    for (int kk = 0; kk < 2; kk++) {
      int c = kk * 64 + ks * 16;
      offB[n][kk] = brow * 128 + (c ^ ((brow & 7) << 4));
    }
  }

  f32x4 zero4 = {0.f, 0.f, 0.f, 0.f};
  f32x4 gacc[4][2], uacc[4][2];
  #pragma unroll
  for (int m = 0; m < 4; m++)
    #pragma unroll
    for (int n = 0; n < 2; n++) { gacc[m][n] = zero4; uacc[m][n] = zero4; }

  auto STAGE = [&](int p, int k0) {
    char* b = lds[p];
    #pragma unroll
    for (int j = 0; j < 4; j++)
      gload16(srcA[j] + k0, b + j * 4096 + wave * 1024);
    #pragma unroll
    for (int j = 0; j < 2; j++) {
      gload16(srcBg[j] + k0, b + 16384 + j * 4096 + wave * 1024);
      gload16(srcBu[j] + k0, b + 24576 + j * 4096 + wave * 1024);
    }
  };

  const int NT = H / 64;  // 32
  STAGE(0, 0);
  pipe_fence();
  for (int t = 0; t < NT; ++t) {
    int p = t & 1;
    if (t + 1 < NT) STAGE(p ^ 1, (t + 1) * 128);
    const char* A = lds[p];
    const char* G = lds[p] + 16384;
    const char* U = lds[p] + 24576;
    #pragma unroll
    for (int kk = 0; kk < 2; kk++) {
      s16x8 a[4], g[2], u[2];
      #pragma unroll
      for (int m = 0; m < 4; m++) a[m] = *(const s16x8*)(A + offA[m][kk]);
      #pragma unroll
      for (int n = 0; n < 2; n++) {
        g[n] = *(const s16x8*)(G + offB[n][kk]);
        u[n] = *(const s16x8*)(U + offB[n][kk]);
      }
      #pragma unroll
      for (int m = 0; m < 4; m++) {
        #pragma unroll
        for (int n = 0; n < 2; n++) {
          gacc[m][n] = mfma16(a[m], g[n], gacc[m][n]);
          uacc[m][n] = mfma16(a[m], u[n], uacc[m][n]);
        }
      }
    }
    pipe_fence();
  }

  #pragma unroll
  for (int m = 0; m < 4; m++) {
    #pragma unroll
    for (int n = 0; n < 2; n++) {
      #pragma unroll
      for (int r = 0; r < 4; r++) {
        int lr = wr * 64 + m * 16 + ks * 4 + r;
        int col = by * 64 + wc * 32 + n * 16 + la;
        float g = gacc[m][n][r], u = uacc[m][n][r];
        float a = g / (1.0f + __expf(-g)) * u;
        if (gather && (bx * 128 + lr) >= cnt) a = 0.0f;
        act[(size_t)(rowBase + lr) * Nout + col] = f2bf(a);
      }
    }
  }
}

// ---------------- down GEMM, 2-phase prefetch ----------------
// C tile 128 rows x 64 cols; A = act bf16 [rows][KD]; BT rows = out cols [H][KD].
template <int KD, bool SCATTER>
__global__ __launch_bounds__(256, 3) void k_down(
    const u16* __restrict__ act, const u16* __restrict__ BT, float* __restrict__ y,
    const int* __restrict__ perm, const float* __restrict__ wgt,
    const int* __restrict__ counts, const int* __restrict__ offs) {
  int bx = blockIdx.x, by = blockIdx.y, e = blockIdx.z;
  int cnt = NTOK, rowBase = bx * 128;
  const u16* B = BT;
  if (SCATTER) {
    cnt = counts[e];
    if (bx * 128 >= cnt) return;
    rowBase = offs[e] + bx * 128;
    B = BT + (size_t)e * H * KD;
  }
  B += (size_t)by * 64 * KD;

  __shared__ char lds[2][24576];  // A:0..16K, B:16K..24K

  int tid = threadIdx.x;
  int wave = tid >> 6, lane = tid & 63;
  int wr = wave >> 1, wc = wave & 1;
  int la = lane & 15, ks = lane >> 4;

  int rIn = tid >> 3;
  int csrc = ((tid & 7) << 4) ^ ((rIn & 7) << 4);
  const char* srcA[4];
  const char* srcB[2];
  #pragma unroll
  for (int j = 0; j < 4; j++) {
    int row = j * 32 + rIn;
    srcA[j] = (const char*)act + ((size_t)(rowBase + row) * KD) * 2 + csrc;
  }
  #pragma unroll
  for (int j = 0; j < 2; j++) {
    int row = j * 32 + rIn;
    srcB[j] = (const char*)B + ((size_t)row * KD) * 2 + csrc;
  }

  int offA[4][2], offB[2][2];
  #pragma unroll
  for (int m = 0; m < 4; m++) {
    int arow = wr * 64 + m * 16 + la;
    #pragma unroll
    for (int kk = 0; kk < 2; kk++) {
      int c = kk * 64 + ks * 16;
      offA[m][kk] = arow * 128 + (c ^ ((arow & 7) << 4));
    }
  }
  #pragma unroll
  for (int n = 0; n < 2; n++) {
    int brow = wc * 32 + n * 16 + la;
    #pragma unroll
    for (int kk = 0; kk < 2; kk++) {
      int c = kk * 64 + ks * 16;
      offB[n][kk] = brow * 128 + (c ^ ((brow & 7) << 4));
    }
  }

  f32x4 zero4 = {0.f, 0.f, 0.f, 0.f};
  f32x4 acc[4][2];
  #pragma unroll
  for (int m = 0; m < 4; m++)
    #pragma unroll
    for (int n = 0; n < 2; n++) acc[m][n] = zero4;

  auto STAGE = [&](int p, int k0) {
    char* b = lds[p];
    #pragma unroll
    for (int j = 0; j < 4; j++)
      gload16(srcA[j] + k0, b + j * 4096 + wave * 1024);
    #pragma unroll
    for (int j = 0; j < 2; j++)
      gload16(srcB[j] + k0, b + 16384 + j * 4096 + wave * 1024);
  };

  const int NT = KD / 64;
  STAGE(0, 0);
  pipe_fence();
  for (int t = 0; t < NT; ++t) {
    int p = t & 1;
    if (t + 1 < NT) STAGE(p ^ 1, (t + 1) * 128);
    const char* A = lds[p];
    const char* Bb = lds[p] + 16384;
    #pragma unroll
    for (int kk = 0; kk < 2; kk++) {
      s16x8 a[4], b[2];
      #pragma unroll
      for (int m = 0; m < 4; m++) a[m] = *(const s16x8*)(A + offA[m][kk]);
      #pragma unroll
      for (int n = 0; n < 2; n++) b[n] = *(const s16x8*)(Bb + offB[n][kk]);
      #pragma unroll
      for (int m = 0; m < 4; m++)
        #pragma unroll
        for (int n = 0; n < 2; n++) acc[m][n] = mfma16(a[m], b[n], acc[m][n]);
    }
    pipe_fence();
  }

  #pragma unroll
  for (int m = 0; m < 4; m++) {
    #pragma unroll
    for (int n = 0; n < 2; n++) {
      #pragma unroll
      for (int r = 0; r < 4; r++) {
        int lr = wr * 64 + m * 16 + ks * 4 + r;
        int col = by * 64 + wc * 32 + n * 16 + la;
        float v = acc[m][n][r];
        if (SCATTER) {
          if (bx * 128 + lr < cnt) {
            int si = rowBase + lr;
            atomicAdd(&y[(size_t)perm[si] * H + col], wgt[si] * v);
          }
        } else {
          y[(size_t)(bx * 128 + lr) * H + col] = v;
        }
      }
    }
  }
}

// ---------------- host launch ----------------

extern "C" void kernel_launch(void* const* d_in, const int* in_sizes, int n_in,
                              void* d_out, int out_size, void* d_ws, size_t ws_size,
                              hipStream_t stream) {
  const float* x   = (const float*)d_in[0];
  const float* gw  = (const float*)d_in[1];
  const float* Wg  = (const float*)d_in[2];
  const float* Wu  = (const float*)d_in[3];
  const float* Wd  = (const float*)d_in[4];
  const float* sWg = (const float*)d_in[5];
  const float* sWu = (const float*)d_in[6];
  const float* sWd = (const float*)d_in[7];
  float* y = (float*)d_out;

  char* w = (char*)d_ws;
  auto alloc = [&](size_t bytes) {
    char* p = w;
    w += (bytes + 255) & ~(size_t)255;
    return p;
  };
  u16* xbf   = (u16*)alloc((size_t)NTOK * H * 2);
  u16* WgT   = (u16*)alloc((size_t)NE * MDIM * H * 2);
  u16* WuT   = (u16*)alloc((size_t)NE * MDIM * H * 2);
  u16* WdT   = (u16*)alloc((size_t)NE * H * MDIM * 2);
  u16* sWgT  = (u16*)alloc((size_t)MS * H * 2);
  u16* sWuT  = (u16*)alloc((size_t)MS * H * 2);
  u16* sWdT  = (u16*)alloc((size_t)H * MS * 2);
  u16* act_s = (u16*)alloc((size_t)NTOK * MS * 2);
  u16* act_r = (u16*)alloc((size_t)ACT_R_ROWS * MDIM * 2);
  int*   te     = (int*)alloc((size_t)NTOK * 2 * 4);
  float* tw     = (float*)alloc((size_t)NTOK * 2 * 4);
  int*   slot   = (int*)alloc((size_t)NTOK * 2 * 4);
  int*   counts = (int*)alloc(64);
  int*   offs   = (int*)alloc(64);
  int*   perm   = (int*)alloc((size_t)ACT_R_ROWS * 4);
  float* wgt    = (float*)alloc((size_t)ACT_R_ROWS * 4);

  k_zero<<<1, 64, 0, stream>>>(counts);

  int n8 = NTOK * H / 8;
  k_cvt<<<(n8 + 255) / 256, 256, 0, stream>>>(x, xbf, n8);
  // weight transposes: src [R][C] fp32 -> dst [C][R] bf16
  k_t64<<<dim3(MDIM / 64, H / 64, NE), 256, 0, stream>>>(Wg, WgT, H, MDIM, (long)H * MDIM, (long)MDIM * H);
  k_t64<<<dim3(MDIM / 64, H / 64, NE), 256, 0, stream>>>(Wu, WuT, H, MDIM, (long)H * MDIM, (long)MDIM * H);
  k_t64<<<dim3(H / 64, MDIM / 64, NE), 256, 0, stream>>>(Wd, WdT, MDIM, H, (long)MDIM * H, (long)H * MDIM);
  k_t64<<<dim3(MS / 64, H / 64, 1), 256, 0, stream>>>(sWg, sWgT, H, MS, 0, 0);
  k_t64<<<dim3(MS / 64, H / 64, 1), 256, 0, stream>>>(sWu, sWuT, H, MS, 0, 0);
  k_t64<<<dim3(H / 64, MS / 64, 1), 256, 0, stream>>>(sWd, sWdT, MS, H, 0, 0);

  k_router<<<NTOK / 4, 256, 0, stream>>>(x, gw, te, tw, slot, counts);
  k_offsets<<<1, 256, 0, stream>>>(counts, offs, perm);
  k_scatter<<<NTOK / 256, 256, 0, stream>>>(te, tw, slot, offs, perm, wgt);

  // merged shared (z=0) + routed (z=1..8) gate/up, fused SwiGLU, 2-phase
  k_gu<<<dim3(NTOK / 128, MS / 64, 1 + NE), 256, 0, stream>>>(
      xbf, WgT, WuT, sWgT, sWuT, act_s, act_r, perm, counts, offs);

  // shared down: dense write into y (must precede routed scatter)
  k_down<MS, false><<<dim3(NTOK / 128, H / 64, 1), 256, 0, stream>>>(
      act_s, sWdT, y, nullptr, nullptr, nullptr, nullptr);
  // routed down: atomic weighted scatter into y
  k_down<MDIM, true><<<dim3(ACT_R_ROWS / 128, H / 64, NE), 256, 0, stream>>>(
      act_r, WdT, y, perm, wgt, counts, offs);
}

// Round 4
// 230.009 us; speedup vs baseline: 1.8641x; 1.1782x over previous
//
#include <hip/hip_runtime.h>

#define H 2048
#define MDIM 512
#define NE 8
#define MS 1024
#define NTOK 2048
#define ACT_R_ROWS 5120

typedef unsigned short u16;
typedef __attribute__((ext_vector_type(8))) short s16x8;
typedef __attribute__((ext_vector_type(4))) float f32x4;

__device__ inline u16 f2bf(float f) {
  unsigned u = __builtin_bit_cast(unsigned, f);
  u = (u + 0x7fffu + ((u >> 16) & 1u)) >> 16;
  return (u16)u;
}

__device__ inline f32x4 mfma16(s16x8 a, s16x8 b, f32x4 c) {
  return __builtin_amdgcn_mfma_f32_16x16x32_bf16(a, b, c, 0, 0, 0);
}

// async global->LDS, 16B per lane. LDS dest wave-uniform base (+lane*16).
__device__ inline void gload16(const void* g, void* l) {
  __builtin_amdgcn_global_load_lds(
      (const __attribute__((address_space(1))) unsigned int*)g,
      (__attribute__((address_space(3))) unsigned int*)l, 16, 0, 0);
}

// ---------------- utility kernels ----------------

__global__ void k_zero(int* counts) {
  if (threadIdx.x < NE) counts[threadIdx.x] = 0;
}

__global__ void k_cvt(const float* __restrict__ src, u16* __restrict__ dst, int n8) {
  int i = blockIdx.x * 256 + threadIdx.x;
  if (i >= n8) return;
  const f32x4* s = (const f32x4*)src;
  f32x4 a = s[2 * i + 0], b = s[2 * i + 1];
  s16x8 o;
  o[0] = (short)f2bf(a[0]); o[1] = (short)f2bf(a[1]);
  o[2] = (short)f2bf(a[2]); o[3] = (short)f2bf(a[3]);
  o[4] = (short)f2bf(b[0]); o[5] = (short)f2bf(b[1]);
  o[6] = (short)f2bf(b[2]); o[7] = (short)f2bf(b[3]);
  ((s16x8*)dst)[i] = o;
}

// vectorized transpose+convert: src fp32 [R][C] -> dst bf16 [C][R], 64x64 tiles
__global__ __launch_bounds__(256) void k_t64(const float* __restrict__ src,
                                             u16* __restrict__ dst,
                                             int R, int C, long ss, long ds) {
  src += (long)blockIdx.z * ss;
  dst += (long)blockIdx.z * ds;
  __shared__ u16 tt[64][66];
  int c0 = blockIdx.x * 64, r0 = blockIdx.y * 64;
  int t = threadIdx.x;
  int cq = (t & 15) * 4, rr = t >> 4;
  #pragma unroll
  for (int i = 0; i < 4; i++) {
    int row = rr + i * 16;
    f32x4 v = *(const f32x4*)&src[(long)(r0 + row) * C + c0 + cq];
    tt[cq + 0][row] = f2bf(v[0]);
    tt[cq + 1][row] = f2bf(v[1]);
    tt[cq + 2][row] = f2bf(v[2]);
    tt[cq + 3][row] = f2bf(v[3]);
  }
  __syncthreads();
  int c = t >> 2, ch = t & 3;
  #pragma unroll
  for (int h = 0; h < 2; h++) {
    int chunk = ch + h * 4;
    const u16* p = &tt[c][chunk * 8];
    s16x8 o;
    #pragma unroll
    for (int w0 = 0; w0 < 8; w0++) o[w0] = (short)p[w0];
    *(s16x8*)&dst[(long)(c0 + c) * R + r0 + chunk * 8] = o;
  }
}

// ---------------- router (fp64 logits, top-2 softmax) ----------------

__global__ void k_router(const float* __restrict__ x, const float* __restrict__ gw,
                         int* te, float* tw, int* slot, int* counts) {
  int n = blockIdx.x * 4 + (threadIdx.x >> 6);
  int lane = threadIdx.x & 63;
  double acc[NE];
  #pragma unroll
  for (int e = 0; e < NE; e++) acc[e] = 0.0;
  for (int j = lane; j < H; j += 64) {
    float xv = x[(long)n * H + j];
    #pragma unroll
    for (int e = 0; e < NE; e++) acc[e] += (double)xv * (double)gw[e * H + j];
  }
  #pragma unroll
  for (int off = 32; off; off >>= 1) {
    #pragma unroll
    for (int e = 0; e < NE; e++) acc[e] += __shfl_xor(acc[e], off);
  }
  if (lane == 0) {
    int b0 = 0; double v0 = acc[0];
    for (int e = 1; e < NE; e++) { if (acc[e] > v0) { v0 = acc[e]; b0 = e; } }
    int b1 = -1; double v1 = -1e300;
    for (int e = 0; e < NE; e++) { if (e != b0 && acc[e] > v1) { v1 = acc[e]; b1 = e; } }
    double ex = exp(v1 - v0);
    te[n * 2] = b0; te[n * 2 + 1] = b1;
    tw[n * 2] = (float)(1.0 / (1.0 + ex));
    tw[n * 2 + 1] = (float)(ex / (1.0 + ex));
    slot[n * 2] = atomicAdd(&counts[b0], 1);
    slot[n * 2 + 1] = atomicAdd(&counts[b1], 1);
  }
}

__global__ void k_offsets(const int* counts, int* offs, int* perm) {
  if (threadIdx.x == 0) {
    int off = 0;
    for (int e = 0; e < NE; e++) { offs[e] = off; off += ((counts[e] + 127) >> 7) << 7; }
    offs[NE] = off;
  }
  for (int i = threadIdx.x; i < ACT_R_ROWS; i += blockDim.x) perm[i] = 0;
}

__global__ void k_scatter(const int* te, const float* tw, const int* slot,
                          const int* offs, int* perm, float* wgt) {
  int n = blockIdx.x * 256 + threadIdx.x;
  if (n >= NTOK) return;
  #pragma unroll
  for (int k = 0; k < 2; k++) {
    int e = te[n * 2 + k];
    int idx = offs[e] + slot[n * 2 + k];
    perm[idx] = n;
    wgt[idx] = tw[n * 2 + k];
  }
}

// ---------------- fused gate+up+SwiGLU GEMM, counted-vmcnt depth-2 ----------------
// C tile 128 rows x 64 cols. Group g = (by,z): g<16 shared; else routed e.
// Grid 1-D 1280 = 80 groups x 16 bx, XCD-swizzled (group -> one XCD).
__global__ __launch_bounds__(256, 2) void k_gu(
    const u16* __restrict__ xbf, const u16* __restrict__ WgT, const u16* __restrict__ WuT,
    const u16* __restrict__ sWgT, const u16* __restrict__ sWuT,
    u16* __restrict__ act_s, u16* __restrict__ act_r,
    const int* __restrict__ perm, const int* __restrict__ counts,
    const int* __restrict__ offs) {
  int lin = blockIdx.x;
  int xcd = lin & 7, jj = lin >> 3;
  int g = xcd + 8 * (jj % 10);   // 80 groups
  int bx = jj / 10;              // 16 row tiles
  const u16 *Bg, *Bu;
  u16* act;
  int Nout, cnt, rowBase, by;
  bool gather;
  if (g < 16) {
    gather = false; by = g;
    cnt = NTOK; rowBase = bx * 128;
    Bg = sWgT + (size_t)by * 64 * H;
    Bu = sWuT + (size_t)by * 64 * H;
    act = act_s; Nout = MS;
  } else {
    gather = true;
    int e = (g - 16) >> 3; by = (g - 16) & 7;
    cnt = counts[e];
    if (bx * 128 >= cnt) return;
    rowBase = offs[e] + bx * 128;
    Bg = WgT + ((size_t)e * MDIM + (size_t)by * 64) * H;
    Bu = WuT + ((size_t)e * MDIM + (size_t)by * 64) * H;
    act = act_r; Nout = MDIM;
  }

  __shared__ char lds[2][32768];  // A:0..16K, Bg:16K..24K, Bu:24K..32K

  int tid = threadIdx.x;
  int wave = tid >> 6, lane = tid & 63;
  int wr = wave >> 1, wc = wave & 1;
  int la = lane & 15, ks = lane >> 4;

  // staging sources (pre-swizzled chunk; rule #21 both-sides)
  int rIn = tid >> 3;
  int csrc = ((tid & 7) << 4) ^ ((rIn & 7) << 4);
  const char* srcA[4];
  const char* srcBg[2];
  const char* srcBu[2];
  #pragma unroll
  for (int j = 0; j < 4; j++) {
    int row = j * 32 + rIn;
    int tok = gather ? perm[rowBase + row] : (rowBase + row);
    srcA[j] = (const char*)xbf + (size_t)tok * H * 2 + csrc;
  }
  #pragma unroll
  for (int j = 0; j < 2; j++) {
    int row = j * 32 + rIn;
    srcBg[j] = (const char*)Bg + (size_t)row * H * 2 + csrc;
    srcBu[j] = (const char*)Bu + (size_t)row * H * 2 + csrc;
  }

  // fragment read offsets (swizzled), relative to buffer base
  int offA[4][2], offB[2][2];
  #pragma unroll
  for (int m = 0; m < 4; m++) {
    int arow = wr * 64 + m * 16 + la;
    #pragma unroll
    for (int kk = 0; kk < 2; kk++) {
      int c = kk * 64 + ks * 16;
      offA[m][kk] = arow * 128 + (c ^ ((arow & 7) << 4));
    }
  }
  #pragma unroll
  for (int n = 0; n < 2; n++) {
    int brow = wc * 32 + n * 16 + la;
    #pragma unroll
    for (int kk = 0; kk < 2; kk++) {
      int c = kk * 64 + ks * 16;
      offB[n][kk] = brow * 128 + (c ^ ((brow & 7) << 4));
    }
  }

  f32x4 zero4 = {0.f, 0.f, 0.f, 0.f};
  f32x4 gacc[4][2], uacc[4][2];
  #pragma unroll
  for (int m = 0; m < 4; m++)
    #pragma unroll
    for (int n = 0; n < 2; n++) { gacc[m][n] = zero4; uacc[m][n] = zero4; }

  auto STAGE = [&](int p, int k0) {
    char* b = lds[p];
    #pragma unroll
    for (int j = 0; j < 4; j++)
      gload16(srcA[j] + k0, b + j * 4096 + wave * 1024);
    #pragma unroll
    for (int j = 0; j < 2; j++) {
      gload16(srcBg[j] + k0, b + 16384 + j * 4096 + wave * 1024);
      gload16(srcBu[j] + k0, b + 24576 + j * 4096 + wave * 1024);
    }
  };

  const int NT = H / 64;  // 32
  STAGE(0, 0);
  STAGE(1, 128);
  asm volatile("s_waitcnt vmcnt(8)" ::: "memory");
  __builtin_amdgcn_sched_barrier(0);
  __builtin_amdgcn_s_barrier();

  for (int t = 0; t < NT; ++t) {
    int p = t & 1;
    const char* A = lds[p];
    const char* G = lds[p] + 16384;
    const char* U = lds[p] + 24576;
    s16x8 af[2][4], gf[2][2], uf[2][2];
    #pragma unroll
    for (int kk = 0; kk < 2; kk++) {
      #pragma unroll
      for (int m = 0; m < 4; m++) af[kk][m] = *(const s16x8*)(A + offA[m][kk]);
      #pragma unroll
      for (int n = 0; n < 2; n++) {
        gf[kk][n] = *(const s16x8*)(G + offB[n][kk]);
        uf[kk][n] = *(const s16x8*)(U + offB[n][kk]);
      }
    }
    asm volatile("s_waitcnt lgkmcnt(0)" ::: "memory");
    __builtin_amdgcn_sched_barrier(0);
    __builtin_amdgcn_s_barrier();           // all waves done reading buf p
    if (t + 2 < NT) STAGE(p, (t + 2) * 128);  // overwrite buf p (reads retired)
    __builtin_amdgcn_sched_barrier(0);
    #pragma unroll
    for (int kk = 0; kk < 2; kk++) {
      #pragma unroll
      for (int m = 0; m < 4; m++) {
        #pragma unroll
        for (int n = 0; n < 2; n++) {
          gacc[m][n] = mfma16(af[kk][m], gf[kk][n], gacc[m][n]);
          uacc[m][n] = mfma16(af[kk][m], uf[kk][n], uacc[m][n]);
        }
      }
    }
    if (t + 2 < NT) { asm volatile("s_waitcnt vmcnt(8)" ::: "memory"); }
    else            { asm volatile("s_waitcnt vmcnt(0)" ::: "memory"); }
    __builtin_amdgcn_sched_barrier(0);
    __builtin_amdgcn_s_barrier();           // publish buf p^1 (tile t+1)
  }

  #pragma unroll
  for (int m = 0; m < 4; m++) {
    #pragma unroll
    for (int n = 0; n < 2; n++) {
      #pragma unroll
      for (int r = 0; r < 4; r++) {
        int lr = wr * 64 + m * 16 + ks * 4 + r;
        int col = by * 64 + wc * 32 + n * 16 + la;
        float gg = gacc[m][n][r], uu = uacc[m][n][r];
        float a = gg / (1.0f + __expf(-gg)) * uu;
        if (gather && (bx * 128 + lr) >= cnt) a = 0.0f;
        act[(size_t)(rowBase + lr) * Nout + col] = f2bf(a);
      }
    }
  }
}

// ---------------- merged down GEMM (shared + routed), counted-vmcnt ----------------
// C tile 128 rows x 64 cols. Groups: g<32 shared (by=g); else routed e,by.
// Grid 1-D 4608 = 288 groups x 16 bx, XCD-swizzled. y accumulated via atomicAdd
// (y pre-zeroed).
__global__ __launch_bounds__(256, 3) void k_down2(
    const u16* __restrict__ act_s, const u16* __restrict__ act_r,
    const u16* __restrict__ sWdT, const u16* __restrict__ WdT,
    float* __restrict__ y,
    const int* __restrict__ perm, const float* __restrict__ wgt,
    const int* __restrict__ counts, const int* __restrict__ offs) {
  int lin = blockIdx.x;
  int xcd = lin & 7, jj = lin >> 3;
  int g = xcd + 8 * (jj % 36);   // 288 groups
  int bx = jj / 36;              // 16 row tiles
  const u16 *A, *B;
  int KD, NT, cnt, rowBase, by;
  bool routed;
  if (g < 32) {
    routed = false; by = g;
    KD = MS; NT = MS / 64;
    cnt = NTOK; rowBase = bx * 128;
    A = act_s + (size_t)rowBase * MS;
    B = sWdT + (size_t)by * 64 * MS;
  } else {
    routed = true;
    int e = (g - 32) >> 5; by = (g - 32) & 31;
    KD = MDIM; NT = MDIM / 64;
    cnt = counts[e];
    if (bx * 128 >= cnt) return;
    rowBase = offs[e] + bx * 128;
    A = act_r + (size_t)rowBase * MDIM;
    B = WdT + ((size_t)e * H + (size_t)by * 64) * MDIM;
  }

  __shared__ char lds[2][24576];  // A:0..16K, B:16K..24K

  int tid = threadIdx.x;
  int wave = tid >> 6, lane = tid & 63;
  int wr = wave >> 1, wc = wave & 1;
  int la = lane & 15, ks = lane >> 4;

  int rIn = tid >> 3;
  int csrc = ((tid & 7) << 4) ^ ((rIn & 7) << 4);
  const char* srcA[4];
  const char* srcB[2];
  #pragma unroll
  for (int j = 0; j < 4; j++) {
    int row = j * 32 + rIn;
    srcA[j] = (const char*)A + (size_t)row * KD * 2 + csrc;
  }
  #pragma unroll
  for (int j = 0; j < 2; j++) {
    int row = j * 32 + rIn;
    srcB[j] = (const char*)B + (size_t)row * KD * 2 + csrc;
  }

  int offA[4][2], offB[2][2];
  #pragma unroll
  for (int m = 0; m < 4; m++) {
    int arow = wr * 64 + m * 16 + la;
    #pragma unroll
    for (int kk = 0; kk < 2; kk++) {
      int c = kk * 64 + ks * 16;
      offA[m][kk] = arow * 128 + (c ^ ((arow & 7) << 4));
    }
  }
  #pragma unroll
  for (int n = 0; n < 2; n++) {
    int brow = wc * 32 + n * 16 + la;
    #pragma unroll
    for (int kk = 0; kk < 2; kk++) {
      int c = kk * 64 + ks * 16;
      offB[n][kk] = brow * 128 + (c ^ ((brow & 7) << 4));
    }
  }

  f32x4 zero4 = {0.f, 0.f, 0.f, 0.f};
  f32x4 acc[4][2];
  #pragma unroll
  for (int m = 0; m < 4; m++)
    #pragma unroll
    for (int n = 0; n < 2; n++) acc[m][n] = zero4;

  auto STAGE = [&](int p, int k0) {
    char* b = lds[p];
    #pragma unroll
    for (int j = 0; j < 4; j++)
      gload16(srcA[j] + k0, b + j * 4096 + wave * 1024);
    #pragma unroll
    for (int j = 0; j < 2; j++)
      gload16(srcB[j] + k0, b + 16384 + j * 4096 + wave * 1024);
  };

  STAGE(0, 0);
  STAGE(1, 128);
  asm volatile("s_waitcnt vmcnt(6)" ::: "memory");
  __builtin_amdgcn_sched_barrier(0);
  __builtin_amdgcn_s_barrier();

  for (int t = 0; t < NT; ++t) {
    int p = t & 1;
    const char* Ab = lds[p];
    const char* Bb = lds[p] + 16384;
    s16x8 af[2][4], bf[2][2];
    #pragma unroll
    for (int kk = 0; kk < 2; kk++) {
      #pragma unroll
      for (int m = 0; m < 4; m++) af[kk][m] = *(const s16x8*)(Ab + offA[m][kk]);
      #pragma unroll
      for (int n = 0; n < 2; n++) bf[kk][n] = *(const s16x8*)(Bb + offB[n][kk]);
    }
    asm volatile("s_waitcnt lgkmcnt(0)" ::: "memory");
    __builtin_amdgcn_sched_barrier(0);
    __builtin_amdgcn_s_barrier();
    if (t + 2 < NT) STAGE(p, (t + 2) * 128);
    __builtin_amdgcn_sched_barrier(0);
    #pragma unroll
    for (int kk = 0; kk < 2; kk++) {
      #pragma unroll
      for (int m = 0; m < 4; m++)
        #pragma unroll
        for (int n = 0; n < 2; n++) acc[m][n] = mfma16(af[kk][m], bf[kk][n], acc[m][n]);
    }
    if (t + 2 < NT) { asm volatile("s_waitcnt vmcnt(6)" ::: "memory"); }
    else            { asm volatile("s_waitcnt vmcnt(0)" ::: "memory"); }
    __builtin_amdgcn_sched_barrier(0);
    __builtin_amdgcn_s_barrier();
  }

  #pragma unroll
  for (int m = 0; m < 4; m++) {
    #pragma unroll
    for (int n = 0; n < 2; n++) {
      #pragma unroll
      for (int r = 0; r < 4; r++) {
        int lr = wr * 64 + m * 16 + ks * 4 + r;
        int col = by * 64 + wc * 32 + n * 16 + la;
        float v = acc[m][n][r];
        if (routed) {
          if (bx * 128 + lr < cnt) {
            int si = rowBase + lr;
            atomicAdd(&y[(size_t)perm[si] * H + col], wgt[si] * v);
          }
        } else {
          atomicAdd(&y[(size_t)(rowBase + lr) * H + col], v);
        }
      }
    }
  }
}

// ---------------- host launch ----------------

extern "C" void kernel_launch(void* const* d_in, const int* in_sizes, int n_in,
                              void* d_out, int out_size, void* d_ws, size_t ws_size,
                              hipStream_t stream) {
  const float* x   = (const float*)d_in[0];
  const float* gw  = (const float*)d_in[1];
  const float* Wg  = (const float*)d_in[2];
  const float* Wu  = (const float*)d_in[3];
  const float* Wd  = (const float*)d_in[4];
  const float* sWg = (const float*)d_in[5];
  const float* sWu = (const float*)d_in[6];
  const float* sWd = (const float*)d_in[7];
  float* y = (float*)d_out;

  char* w = (char*)d_ws;
  auto alloc = [&](size_t bytes) {
    char* p = w;
    w += (bytes + 255) & ~(size_t)255;
    return p;
  };
  u16* xbf   = (u16*)alloc((size_t)NTOK * H * 2);
  u16* WgT   = (u16*)alloc((size_t)NE * MDIM * H * 2);
  u16* WuT   = (u16*)alloc((size_t)NE * MDIM * H * 2);
  u16* WdT   = (u16*)alloc((size_t)NE * H * MDIM * 2);
  u16* sWgT  = (u16*)alloc((size_t)MS * H * 2);
  u16* sWuT  = (u16*)alloc((size_t)MS * H * 2);
  u16* sWdT  = (u16*)alloc((size_t)H * MS * 2);
  u16* act_s = (u16*)alloc((size_t)NTOK * MS * 2);
  u16* act_r = (u16*)alloc((size_t)ACT_R_ROWS * MDIM * 2);
  int*   te     = (int*)alloc((size_t)NTOK * 2 * 4);
  float* tw     = (float*)alloc((size_t)NTOK * 2 * 4);
  int*   slot   = (int*)alloc((size_t)NTOK * 2 * 4);
  int*   counts = (int*)alloc(64);
  int*   offs   = (int*)alloc(64);
  int*   perm   = (int*)alloc((size_t)ACT_R_ROWS * 4);
  float* wgt    = (float*)alloc((size_t)ACT_R_ROWS * 4);

  k_zero<<<1, 64, 0, stream>>>(counts);
  hipMemsetAsync(y, 0, (size_t)out_size * 4, stream);

  int n8 = NTOK * H / 8;
  k_cvt<<<(n8 + 255) / 256, 256, 0, stream>>>(x, xbf, n8);
  // weight transposes: src [R][C] fp32 -> dst [C][R] bf16
  k_t64<<<dim3(MDIM / 64, H / 64, NE), 256, 0, stream>>>(Wg, WgT, H, MDIM, (long)H * MDIM, (long)MDIM * H);
  k_t64<<<dim3(MDIM / 64, H / 64, NE), 256, 0, stream>>>(Wu, WuT, H, MDIM, (long)H * MDIM, (long)MDIM * H);
  k_t64<<<dim3(H / 64, MDIM / 64, NE), 256, 0, stream>>>(Wd, WdT, MDIM, H, (long)MDIM * H, (long)H * MDIM);
  k_t64<<<dim3(MS / 64, H / 64, 1), 256, 0, stream>>>(sWg, sWgT, H, MS, 0, 0);
  k_t64<<<dim3(MS / 64, H / 64, 1), 256, 0, stream>>>(sWu, sWuT, H, MS, 0, 0);
  k_t64<<<dim3(H / 64, MS / 64, 1), 256, 0, stream>>>(sWd, sWdT, MS, H, 0, 0);

  k_router<<<NTOK / 4, 256, 0, stream>>>(x, gw, te, tw, slot, counts);
  k_offsets<<<1, 256, 0, stream>>>(counts, offs, perm);
  k_scatter<<<NTOK / 256, 256, 0, stream>>>(te, tw, slot, offs, perm, wgt);

  // merged shared (g<16) + routed gate/up, fused SwiGLU, counted-vmcnt pipeline
  k_gu<<<80 * 16, 256, 0, stream>>>(
      xbf, WgT, WuT, sWgT, sWuT, act_s, act_r, perm, counts, offs);

  // merged shared + routed down, atomicAdd into zeroed y
  k_down2<<<288 * 16, 256, 0, stream>>>(
      act_s, act_r, sWdT, WdT, y, perm, wgt, counts, offs);
}

// Round 5
// 188.258 us; speedup vs baseline: 2.2775x; 1.2218x over previous
//
#include <hip/hip_runtime.h>

#define H 2048
#define MDIM 512
#define NE 8
#define MS 1024
#define NTOK 2048
#define ACT_R_ROWS 5120

typedef unsigned short u16;
typedef __attribute__((ext_vector_type(8))) short s16x8;
typedef __attribute__((ext_vector_type(4))) float f32x4;

__device__ inline u16 f2bf(float f) {
  unsigned u = __builtin_bit_cast(unsigned, f);
  u = (u + 0x7fffu + ((u >> 16) & 1u)) >> 16;
  return (u16)u;
}

__device__ inline f32x4 mfma16(s16x8 a, s16x8 b, f32x4 c) {
  return __builtin_amdgcn_mfma_f32_16x16x32_bf16(a, b, c, 0, 0, 0);
}

// async global->LDS, 16B per lane. LDS dest wave-uniform base (+lane*16).
__device__ inline void gload16(const void* g, void* l) {
  __builtin_amdgcn_global_load_lds(
      (const __attribute__((address_space(1))) unsigned int*)g,
      (__attribute__((address_space(3))) unsigned int*)l, 16, 0, 0);
}

// ---------------- utility kernels ----------------

__global__ void k_cvt(const float* __restrict__ src, u16* __restrict__ dst, int n8) {
  int i = blockIdx.x * 256 + threadIdx.x;
  if (i >= n8) return;
  const f32x4* s = (const f32x4*)src;
  f32x4 a = s[2 * i + 0], b = s[2 * i + 1];
  s16x8 o;
  o[0] = (short)f2bf(a[0]); o[1] = (short)f2bf(a[1]);
  o[2] = (short)f2bf(a[2]); o[3] = (short)f2bf(a[3]);
  o[4] = (short)f2bf(b[0]); o[5] = (short)f2bf(b[1]);
  o[6] = (short)f2bf(b[2]); o[7] = (short)f2bf(b[3]);
  ((s16x8*)dst)[i] = o;
}

// vectorized transpose+convert: src fp32 [R][C] -> dst bf16 [C][R], 64x64 tiles
__global__ __launch_bounds__(256) void k_t64(const float* __restrict__ src,
                                             u16* __restrict__ dst,
                                             int R, int C, long ss, long ds) {
  src += (long)blockIdx.z * ss;
  dst += (long)blockIdx.z * ds;
  __shared__ u16 tt[64][66];
  int c0 = blockIdx.x * 64, r0 = blockIdx.y * 64;
  int t = threadIdx.x;
  int cq = (t & 15) * 4, rr = t >> 4;
  #pragma unroll
  for (int i = 0; i < 4; i++) {
    int row = rr + i * 16;
    f32x4 v = *(const f32x4*)&src[(long)(r0 + row) * C + c0 + cq];
    tt[cq + 0][row] = f2bf(v[0]);
    tt[cq + 1][row] = f2bf(v[1]);
    tt[cq + 2][row] = f2bf(v[2]);
    tt[cq + 3][row] = f2bf(v[3]);
  }
  __syncthreads();
  int c = t >> 2, ch = t & 3;
  #pragma unroll
  for (int h = 0; h < 2; h++) {
    int chunk = ch + h * 4;
    const u16* p = &tt[c][chunk * 8];
    s16x8 o;
    #pragma unroll
    for (int w0 = 0; w0 < 8; w0++) o[w0] = (short)p[w0];
    *(s16x8*)&dst[(long)(c0 + c) * R + r0 + chunk * 8] = o;
  }
}

// ---------------- router: logits + top-2 (no atomics) ----------------

__global__ void k_logits(const float* __restrict__ x, const float* __restrict__ gw,
                         int* __restrict__ te, float* __restrict__ tw) {
  int n = blockIdx.x * 4 + (threadIdx.x >> 6);
  int lane = threadIdx.x & 63;
  double acc[NE];
  #pragma unroll
  for (int e = 0; e < NE; e++) acc[e] = 0.0;
  for (int j = lane; j < H; j += 64) {
    float xv = x[(long)n * H + j];
    #pragma unroll
    for (int e = 0; e < NE; e++) acc[e] += (double)xv * (double)gw[e * H + j];
  }
  #pragma unroll
  for (int off = 32; off; off >>= 1) {
    #pragma unroll
    for (int e = 0; e < NE; e++) acc[e] += __shfl_xor(acc[e], off);
  }
  if (lane == 0) {
    int b0 = 0; double v0 = acc[0];
    #pragma unroll
    for (int e = 1; e < NE; e++) { if (acc[e] > v0) { v0 = acc[e]; b0 = e; } }
    int b1 = -1; double v1 = -1e300;
    #pragma unroll
    for (int e = 0; e < NE; e++) { if (e != b0 && acc[e] > v1) { v1 = acc[e]; b1 = e; } }
    double ex = exp(v1 - v0);
    te[n * 2] = b0; te[n * 2 + 1] = b1;
    tw[n * 2] = (float)(1.0 / (1.0 + ex));
    tw[n * 2 + 1] = (float)(ex / (1.0 + ex));
  }
}

// single-block deterministic dispatch build: counts, padded offs, perm, wgt.
// Privatized per-thread histogram (static-indexed regs), LDS prefix, ordered
// slot assignment — zero global atomics.
__global__ __launch_bounds__(256) void k_build(
    const int* __restrict__ te, const float* __restrict__ tw,
    int* __restrict__ counts, int* __restrict__ offs,
    int* __restrict__ perm, float* __restrict__ wgt) {
  __shared__ int cnt[256][NE];
  __shared__ int pb[NE];
  int t = threadIdx.x;
  int ebuf[16];
  int lc[NE];
  #pragma unroll
  for (int e = 0; e < NE; e++) lc[e] = 0;
  #pragma unroll
  for (int i = 0; i < 16; i++) {
    int ei = te[t * 16 + i];
    ebuf[i] = ei;
    #pragma unroll
    for (int e = 0; e < NE; e++) lc[e] += (ei == e) ? 1 : 0;
  }
  #pragma unroll
  for (int e = 0; e < NE; e++) cnt[t][e] = lc[e];
  __syncthreads();
  if (t < NE) {  // exclusive prefix over threads for expert t
    int run = 0;
    for (int i = 0; i < 256; i++) { int v = cnt[i][t]; cnt[i][t] = run; run += v; }
    counts[t] = run;
  }
  __syncthreads();
  if (t == 0) {
    int off = 0;
    #pragma unroll
    for (int e = 0; e < NE; e++) {
      pb[e] = off; offs[e] = off;
      off += ((counts[e] + 127) >> 7) << 7;
    }
    offs[NE] = off;
  }
  // init all (incl. padding); real slots overwritten after the barrier
  for (int i = t; i < ACT_R_ROWS; i += 256) { perm[i] = 0; wgt[i] = 0.f; }
  __syncthreads();
  int run2[NE];
  #pragma unroll
  for (int e = 0; e < NE; e++) run2[e] = cnt[t][e];
  #pragma unroll
  for (int i = 0; i < 16; i++) {
    int ei = ebuf[i];
    int idx = 0;
    #pragma unroll
    for (int e = 0; e < NE; e++) {
      if (ei == e) idx = pb[e] + run2[e];
      run2[e] += (ei == e) ? 1 : 0;
    }
    perm[idx] = (t * 16 + i) >> 1;
    wgt[idx] = tw[t * 16 + i];
  }
}

// ---------------- fused gate+up+SwiGLU GEMM, counted-vmcnt depth-2 ----------------
// C tile 128 rows x 64 cols. Group g = (by,z): g<16 shared; else routed e.
// Grid 1-D 1280 = 80 groups x 16 bx, XCD-swizzled (group -> one XCD).
__global__ __launch_bounds__(256, 2) void k_gu(
    const u16* __restrict__ xbf, const u16* __restrict__ WgT, const u16* __restrict__ WuT,
    const u16* __restrict__ sWgT, const u16* __restrict__ sWuT,
    u16* __restrict__ act_s, u16* __restrict__ act_r,
    const int* __restrict__ perm, const int* __restrict__ counts,
    const int* __restrict__ offs) {
  int lin = blockIdx.x;
  int xcd = lin & 7, jj = lin >> 3;
  int g = xcd + 8 * (jj % 10);   // 80 groups
  int bx = jj / 10;              // 16 row tiles
  const u16 *Bg, *Bu;
  u16* act;
  int Nout, cnt, rowBase, by;
  bool gather;
  if (g < 16) {
    gather = false; by = g;
    cnt = NTOK; rowBase = bx * 128;
    Bg = sWgT + (size_t)by * 64 * H;
    Bu = sWuT + (size_t)by * 64 * H;
    act = act_s; Nout = MS;
  } else {
    gather = true;
    int e = (g - 16) >> 3; by = (g - 16) & 7;
    cnt = counts[e];
    if (bx * 128 >= cnt) return;
    rowBase = offs[e] + bx * 128;
    Bg = WgT + ((size_t)e * MDIM + (size_t)by * 64) * H;
    Bu = WuT + ((size_t)e * MDIM + (size_t)by * 64) * H;
    act = act_r; Nout = MDIM;
  }

  __shared__ char lds[2][32768];  // A:0..16K, Bg:16K..24K, Bu:24K..32K

  int tid = threadIdx.x;
  int wave = tid >> 6, lane = tid & 63;
  int wr = wave >> 1, wc = wave & 1;
  int la = lane & 15, ks = lane >> 4;

  // staging sources (pre-swizzled chunk; rule #21 both-sides)
  int rIn = tid >> 3;
  int csrc = ((tid & 7) << 4) ^ ((rIn & 7) << 4);
  const char* srcA[4];
  const char* srcBg[2];
  const char* srcBu[2];
  #pragma unroll
  for (int j = 0; j < 4; j++) {
    int row = j * 32 + rIn;
    int tok = gather ? perm[rowBase + row] : (rowBase + row);
    srcA[j] = (const char*)xbf + (size_t)tok * H * 2 + csrc;
  }
  #pragma unroll
  for (int j = 0; j < 2; j++) {
    int row = j * 32 + rIn;
    srcBg[j] = (const char*)Bg + (size_t)row * H * 2 + csrc;
    srcBu[j] = (const char*)Bu + (size_t)row * H * 2 + csrc;
  }

  // fragment read offsets (swizzled), relative to buffer base
  int offA[4][2], offB[2][2];
  #pragma unroll
  for (int m = 0; m < 4; m++) {
    int arow = wr * 64 + m * 16 + la;
    #pragma unroll
    for (int kk = 0; kk < 2; kk++) {
      int c = kk * 64 + ks * 16;
      offA[m][kk] = arow * 128 + (c ^ ((arow & 7) << 4));
    }
  }
  #pragma unroll
  for (int n = 0; n < 2; n++) {
    int brow = wc * 32 + n * 16 + la;
    #pragma unroll
    for (int kk = 0; kk < 2; kk++) {
      int c = kk * 64 + ks * 16;
      offB[n][kk] = brow * 128 + (c ^ ((brow & 7) << 4));
    }
  }

  f32x4 zero4 = {0.f, 0.f, 0.f, 0.f};
  f32x4 gacc[4][2], uacc[4][2];
  #pragma unroll
  for (int m = 0; m < 4; m++)
    #pragma unroll
    for (int n = 0; n < 2; n++) { gacc[m][n] = zero4; uacc[m][n] = zero4; }

  auto STAGE = [&](int p, int k0) {
    char* b = lds[p];
    #pragma unroll
    for (int j = 0; j < 4; j++)
      gload16(srcA[j] + k0, b + j * 4096 + wave * 1024);
    #pragma unroll
    for (int j = 0; j < 2; j++) {
      gload16(srcBg[j] + k0, b + 16384 + j * 4096 + wave * 1024);
      gload16(srcBu[j] + k0, b + 24576 + j * 4096 + wave * 1024);
    }
  };

  const int NT = H / 64;  // 32
  STAGE(0, 0);
  STAGE(1, 128);
  asm volatile("s_waitcnt vmcnt(8)" ::: "memory");
  __builtin_amdgcn_sched_barrier(0);
  __builtin_amdgcn_s_barrier();

  for (int t = 0; t < NT; ++t) {
    int p = t & 1;
    const char* A = lds[p];
    const char* G = lds[p] + 16384;
    const char* U = lds[p] + 24576;
    s16x8 af[2][4], gf[2][2], uf[2][2];
    #pragma unroll
    for (int kk = 0; kk < 2; kk++) {
      #pragma unroll
      for (int m = 0; m < 4; m++) af[kk][m] = *(const s16x8*)(A + offA[m][kk]);
      #pragma unroll
      for (int n = 0; n < 2; n++) {
        gf[kk][n] = *(const s16x8*)(G + offB[n][kk]);
        uf[kk][n] = *(const s16x8*)(U + offB[n][kk]);
      }
    }
    asm volatile("s_waitcnt lgkmcnt(0)" ::: "memory");
    __builtin_amdgcn_sched_barrier(0);
    __builtin_amdgcn_s_barrier();           // all waves done reading buf p
    if (t + 2 < NT) STAGE(p, (t + 2) * 128);  // overwrite buf p (reads retired)
    __builtin_amdgcn_sched_barrier(0);
    #pragma unroll
    for (int kk = 0; kk < 2; kk++) {
      #pragma unroll
      for (int m = 0; m < 4; m++) {
        #pragma unroll
        for (int n = 0; n < 2; n++) {
          gacc[m][n] = mfma16(af[kk][m], gf[kk][n], gacc[m][n]);
          uacc[m][n] = mfma16(af[kk][m], uf[kk][n], uacc[m][n]);
        }
      }
    }
    if (t + 2 < NT) { asm volatile("s_waitcnt vmcnt(8)" ::: "memory"); }
    else            { asm volatile("s_waitcnt vmcnt(0)" ::: "memory"); }
    __builtin_amdgcn_sched_barrier(0);
    __builtin_amdgcn_s_barrier();           // publish buf p^1 (tile t+1)
  }

  #pragma unroll
  for (int m = 0; m < 4; m++) {
    #pragma unroll
    for (int n = 0; n < 2; n++) {
      #pragma unroll
      for (int r = 0; r < 4; r++) {
        int lr = wr * 64 + m * 16 + ks * 4 + r;
        int col = by * 64 + wc * 32 + n * 16 + la;
        float gg = gacc[m][n][r], uu = uacc[m][n][r];
        float a = gg / (1.0f + __expf(-gg)) * uu;
        if (gather && (bx * 128 + lr) >= cnt) a = 0.0f;
        act[(size_t)(rowBase + lr) * Nout + col] = f2bf(a);
      }
    }
  }
}

// ---------------- merged down GEMM (shared + routed), counted-vmcnt ----------------
// C tile 128 rows x 64 cols. Groups: g<32 shared (by=g); else routed e,by.
// Grid 1-D 4608 = 288 groups x 16 bx, XCD-swizzled. y accumulated via atomicAdd
// (y pre-zeroed).
__global__ __launch_bounds__(256, 3) void k_down2(
    const u16* __restrict__ act_s, const u16* __restrict__ act_r,
    const u16* __restrict__ sWdT, const u16* __restrict__ WdT,
    float* __restrict__ y,
    const int* __restrict__ perm, const float* __restrict__ wgt,
    const int* __restrict__ counts, const int* __restrict__ offs) {
  int lin = blockIdx.x;
  int xcd = lin & 7, jj = lin >> 3;
  int g = xcd + 8 * (jj % 36);   // 288 groups
  int bx = jj / 36;              // 16 row tiles
  const u16 *A, *B;
  int KD, NT, cnt, rowBase, by;
  bool routed;
  if (g < 32) {
    routed = false; by = g;
    KD = MS; NT = MS / 64;
    cnt = NTOK; rowBase = bx * 128;
    A = act_s + (size_t)rowBase * MS;
    B = sWdT + (size_t)by * 64 * MS;
  } else {
    routed = true;
    int e = (g - 32) >> 5; by = (g - 32) & 31;
    KD = MDIM; NT = MDIM / 64;
    cnt = counts[e];
    if (bx * 128 >= cnt) return;
    rowBase = offs[e] + bx * 128;
    A = act_r + (size_t)rowBase * MDIM;
    B = WdT + ((size_t)e * H + (size_t)by * 64) * MDIM;
  }

  __shared__ char lds[2][24576];  // A:0..16K, B:16K..24K

  int tid = threadIdx.x;
  int wave = tid >> 6, lane = tid & 63;
  int wr = wave >> 1, wc = wave & 1;
  int la = lane & 15, ks = lane >> 4;

  int rIn = tid >> 3;
  int csrc = ((tid & 7) << 4) ^ ((rIn & 7) << 4);
  const char* srcA[4];
  const char* srcB[2];
  #pragma unroll
  for (int j = 0; j < 4; j++) {
    int row = j * 32 + rIn;
    srcA[j] = (const char*)A + (size_t)row * KD * 2 + csrc;
  }
  #pragma unroll
  for (int j = 0; j < 2; j++) {
    int row = j * 32 + rIn;
    srcB[j] = (const char*)B + (size_t)row * KD * 2 + csrc;
  }

  int offA[4][2], offB[2][2];
  #pragma unroll
  for (int m = 0; m < 4; m++) {
    int arow = wr * 64 + m * 16 + la;
    #pragma unroll
    for (int kk = 0; kk < 2; kk++) {
      int c = kk * 64 + ks * 16;
      offA[m][kk] = arow * 128 + (c ^ ((arow & 7) << 4));
    }
  }
  #pragma unroll
  for (int n = 0; n < 2; n++) {
    int brow = wc * 32 + n * 16 + la;
    #pragma unroll
    for (int kk = 0; kk < 2; kk++) {
      int c = kk * 64 + ks * 16;
      offB[n][kk] = brow * 128 + (c ^ ((brow & 7) << 4));
    }
  }

  f32x4 zero4 = {0.f, 0.f, 0.f, 0.f};
  f32x4 acc[4][2];
  #pragma unroll
  for (int m = 0; m < 4; m++)
    #pragma unroll
    for (int n = 0; n < 2; n++) acc[m][n] = zero4;

  auto STAGE = [&](int p, int k0) {
    char* b = lds[p];
    #pragma unroll
    for (int j = 0; j < 4; j++)
      gload16(srcA[j] + k0, b + j * 4096 + wave * 1024);
    #pragma unroll
    for (int j = 0; j < 2; j++)
      gload16(srcB[j] + k0, b + 16384 + j * 4096 + wave * 1024);
  };

  STAGE(0, 0);
  STAGE(1, 128);
  asm volatile("s_waitcnt vmcnt(6)" ::: "memory");
  __builtin_amdgcn_sched_barrier(0);
  __builtin_amdgcn_s_barrier();

  for (int t = 0; t < NT; ++t) {
    int p = t & 1;
    const char* Ab = lds[p];
    const char* Bb = lds[p] + 16384;
    s16x8 af[2][4], bf[2][2];
    #pragma unroll
    for (int kk = 0; kk < 2; kk++) {
      #pragma unroll
      for (int m = 0; m < 4; m++) af[kk][m] = *(const s16x8*)(Ab + offA[m][kk]);
      #pragma unroll
      for (int n = 0; n < 2; n++) bf[kk][n] = *(const s16x8*)(Bb + offB[n][kk]);
    }
    asm volatile("s_waitcnt lgkmcnt(0)" ::: "memory");
    __builtin_amdgcn_sched_barrier(0);
    __builtin_amdgcn_s_barrier();
    if (t + 2 < NT) STAGE(p, (t + 2) * 128);
    __builtin_amdgcn_sched_barrier(0);
    #pragma unroll
    for (int kk = 0; kk < 2; kk++) {
      #pragma unroll
      for (int m = 0; m < 4; m++)
        #pragma unroll
        for (int n = 0; n < 2; n++) acc[m][n] = mfma16(af[kk][m], bf[kk][n], acc[m][n]);
    }
    if (t + 2 < NT) { asm volatile("s_waitcnt vmcnt(6)" ::: "memory"); }
    else            { asm volatile("s_waitcnt vmcnt(0)" ::: "memory"); }
    __builtin_amdgcn_sched_barrier(0);
    __builtin_amdgcn_s_barrier();
  }

  #pragma unroll
  for (int m = 0; m < 4; m++) {
    #pragma unroll
    for (int n = 0; n < 2; n++) {
      #pragma unroll
      for (int r = 0; r < 4; r++) {
        int lr = wr * 64 + m * 16 + ks * 4 + r;
        int col = by * 64 + wc * 32 + n * 16 + la;
        float v = acc[m][n][r];
        if (routed) {
          if (bx * 128 + lr < cnt) {
            int si = rowBase + lr;
            atomicAdd(&y[(size_t)perm[si] * H + col], wgt[si] * v);
          }
        } else {
          atomicAdd(&y[(size_t)(rowBase + lr) * H + col], v);
        }
      }
    }
  }
}

// ---------------- host launch ----------------

extern "C" void kernel_launch(void* const* d_in, const int* in_sizes, int n_in,
                              void* d_out, int out_size, void* d_ws, size_t ws_size,
                              hipStream_t stream) {
  const float* x   = (const float*)d_in[0];
  const float* gw  = (const float*)d_in[1];
  const float* Wg  = (const float*)d_in[2];
  const float* Wu  = (const float*)d_in[3];
  const float* Wd  = (const float*)d_in[4];
  const float* sWg = (const float*)d_in[5];
  const float* sWu = (const float*)d_in[6];
  const float* sWd = (const float*)d_in[7];
  float* y = (float*)d_out;

  char* w = (char*)d_ws;
  auto alloc = [&](size_t bytes) {
    char* p = w;
    w += (bytes + 255) & ~(size_t)255;
    return p;
  };
  u16* xbf   = (u16*)alloc((size_t)NTOK * H * 2);
  u16* WgT   = (u16*)alloc((size_t)NE * MDIM * H * 2);
  u16* WuT   = (u16*)alloc((size_t)NE * MDIM * H * 2);
  u16* WdT   = (u16*)alloc((size_t)NE * H * MDIM * 2);
  u16* sWgT  = (u16*)alloc((size_t)MS * H * 2);
  u16* sWuT  = (u16*)alloc((size_t)MS * H * 2);
  u16* sWdT  = (u16*)alloc((size_t)H * MS * 2);
  u16* act_s = (u16*)alloc((size_t)NTOK * MS * 2);
  u16* act_r = (u16*)alloc((size_t)ACT_R_ROWS * MDIM * 2);
  int*   te     = (int*)alloc((size_t)NTOK * 2 * 4);
  float* tw     = (float*)alloc((size_t)NTOK * 2 * 4);
  int*   counts = (int*)alloc(64);
  int*   offs   = (int*)alloc(64);
  int*   perm   = (int*)alloc((size_t)ACT_R_ROWS * 4);
  float* wgt    = (float*)alloc((size_t)ACT_R_ROWS * 4);

  hipMemsetAsync(y, 0, (size_t)out_size * 4, stream);

  int n8 = NTOK * H / 8;
  k_cvt<<<(n8 + 255) / 256, 256, 0, stream>>>(x, xbf, n8);
  // weight transposes: src [R][C] fp32 -> dst [C][R] bf16
  k_t64<<<dim3(MDIM / 64, H / 64, NE), 256, 0, stream>>>(Wg, WgT, H, MDIM, (long)H * MDIM, (long)MDIM * H);
  k_t64<<<dim3(MDIM / 64, H / 64, NE), 256, 0, stream>>>(Wu, WuT, H, MDIM, (long)H * MDIM, (long)MDIM * H);
  k_t64<<<dim3(H / 64, MDIM / 64, NE), 256, 0, stream>>>(Wd, WdT, MDIM, H, (long)MDIM * H, (long)H * MDIM);
  k_t64<<<dim3(MS / 64, H / 64, 1), 256, 0, stream>>>(sWg, sWgT, H, MS, 0, 0);
  k_t64<<<dim3(MS / 64, H / 64, 1), 256, 0, stream>>>(sWu, sWuT, H, MS, 0, 0);
  k_t64<<<dim3(H / 64, MS / 64, 1), 256, 0, stream>>>(sWd, sWdT, MS, H, 0, 0);

  // atomic-free routing
  k_logits<<<NTOK / 4, 256, 0, stream>>>(x, gw, te, tw);
  k_build<<<1, 256, 0, stream>>>(te, tw, counts, offs, perm, wgt);

  // merged shared (g<16) + routed gate/up, fused SwiGLU, counted-vmcnt pipeline
  k_gu<<<80 * 16, 256, 0, stream>>>(
      xbf, WgT, WuT, sWgT, sWuT, act_s, act_r, perm, counts, offs);

  // merged shared + routed down, atomicAdd into zeroed y
  k_down2<<<288 * 16, 256, 0, stream>>>(
      act_s, act_r, sWdT, WdT, y, perm, wgt, counts, offs);
}

// Round 6
// 168.633 us; speedup vs baseline: 2.5425x; 1.1164x over previous
//
#include <hip/hip_runtime.h>

#define H 2048
#define MDIM 512
#define NE 8
#define MS 1024
#define NTOK 2048
#define ACT_R_ROWS 5120

typedef unsigned short u16;
typedef __attribute__((ext_vector_type(8))) short s16x8;
typedef __attribute__((ext_vector_type(4))) float f32x4;

__device__ inline u16 f2bf(float f) {
  unsigned u = __builtin_bit_cast(unsigned, f);
  u = (u + 0x7fffu + ((u >> 16) & 1u)) >> 16;
  return (u16)u;
}
__device__ inline float bf2f(u16 v) {
  return __builtin_bit_cast(float, (unsigned)v << 16);
}

__device__ inline f32x4 mfma16(s16x8 a, s16x8 b, f32x4 c) {
  return __builtin_amdgcn_mfma_f32_16x16x32_bf16(a, b, c, 0, 0, 0);
}

// async global->LDS, 16B per lane. LDS dest wave-uniform base (+lane*16).
__device__ inline void gload16(const void* g, void* l) {
  __builtin_amdgcn_global_load_lds(
      (const __attribute__((address_space(1))) unsigned int*)g,
      (__attribute__((address_space(3))) unsigned int*)l, 16, 0, 0);
}

// ---------------- utility kernels ----------------

__global__ void k_cvt(const float* __restrict__ src, u16* __restrict__ dst, int n8) {
  int i = blockIdx.x * 256 + threadIdx.x;
  if (i >= n8) return;
  const f32x4* s = (const f32x4*)src;
  f32x4 a = s[2 * i + 0], b = s[2 * i + 1];
  s16x8 o;
  o[0] = (short)f2bf(a[0]); o[1] = (short)f2bf(a[1]);
  o[2] = (short)f2bf(a[2]); o[3] = (short)f2bf(a[3]);
  o[4] = (short)f2bf(b[0]); o[5] = (short)f2bf(b[1]);
  o[6] = (short)f2bf(b[2]); o[7] = (short)f2bf(b[3]);
  ((s16x8*)dst)[i] = o;
}

// device transpose tile body: src fp32 [R][C] -> dst bf16 [C][R], 64x64 tile
__device__ inline void tile_t64(const float* __restrict__ src, u16* __restrict__ dst,
                                int R, int C, int bx, int by) {
  __shared__ u16 tt[64][66];
  int c0 = bx * 64, r0 = by * 64;
  int t = threadIdx.x;
  int cq = (t & 15) * 4, rr = t >> 4;
  #pragma unroll
  for (int i = 0; i < 4; i++) {
    int row = rr + i * 16;
    f32x4 v = *(const f32x4*)&src[(long)(r0 + row) * C + c0 + cq];
    tt[cq + 0][row] = f2bf(v[0]);
    tt[cq + 1][row] = f2bf(v[1]);
    tt[cq + 2][row] = f2bf(v[2]);
    tt[cq + 3][row] = f2bf(v[3]);
  }
  __syncthreads();
  int c = t >> 2, ch = t & 3;
  #pragma unroll
  for (int h = 0; h < 2; h++) {
    int chunk = ch + h * 4;
    const u16* p = &tt[c][chunk * 8];
    s16x8 o;
    #pragma unroll
    for (int w0 = 0; w0 < 8; w0++) o[w0] = (short)p[w0];
    *(s16x8*)&dst[(long)(c0 + c) * R + r0 + chunk * 8] = o;
  }
}

// merged weight transpose+convert: all 6 jobs in one dispatch (7680 blocks)
__global__ __launch_bounds__(256) void k_prep(
    const float* __restrict__ Wg, const float* __restrict__ Wu,
    const float* __restrict__ Wd, const float* __restrict__ sWg,
    const float* __restrict__ sWu, const float* __restrict__ sWd,
    u16* __restrict__ WgT, u16* __restrict__ WuT, u16* __restrict__ WdT,
    u16* __restrict__ sWgT, u16* __restrict__ sWuT, u16* __restrict__ sWdT) {
  int b = blockIdx.x;
  const float* src; u16* dst; int R, C, lb;
  if (b < 2048) {               // Wg: [H][MDIM] x8 -> [MDIM][H]
    lb = b; R = H; C = MDIM;
    int z = lb >> 8; lb &= 255;
    src = Wg + (size_t)z * H * MDIM; dst = WgT + (size_t)z * MDIM * H;
  } else if (b < 4096) {        // Wu
    lb = b - 2048; R = H; C = MDIM;
    int z = lb >> 8; lb &= 255;
    src = Wu + (size_t)z * H * MDIM; dst = WuT + (size_t)z * MDIM * H;
  } else if (b < 6144) {        // Wd: [MDIM][H] x8 -> [H][MDIM]
    lb = b - 4096; R = MDIM; C = H;
    int z = lb >> 8; lb &= 255;
    src = Wd + (size_t)z * MDIM * H; dst = WdT + (size_t)z * H * MDIM;
  } else if (b < 6656) {        // sWg: [H][MS] -> [MS][H]
    lb = b - 6144; R = H; C = MS; src = sWg; dst = sWgT;
  } else if (b < 7168) {        // sWu
    lb = b - 6656; R = H; C = MS; src = sWu; dst = sWuT;
  } else {                      // sWd: [MS][H] -> [H][MS]
    lb = b - 7168; R = MS; C = H; src = sWd; dst = sWdT;
  }
  int nbx = C >> 6;
  tile_t64(src, dst, R, C, lb % nbx, lb / nbx);
}

// ---------------- router: logits + top-2 (no atomics) ----------------

__global__ void k_logits(const float* __restrict__ x, const float* __restrict__ gw,
                         int* __restrict__ te, float* __restrict__ tw) {
  int n = blockIdx.x * 4 + (threadIdx.x >> 6);
  int lane = threadIdx.x & 63;
  double acc[NE];
  #pragma unroll
  for (int e = 0; e < NE; e++) acc[e] = 0.0;
  for (int j = lane; j < H; j += 64) {
    float xv = x[(long)n * H + j];
    #pragma unroll
    for (int e = 0; e < NE; e++) acc[e] += (double)xv * (double)gw[e * H + j];
  }
  #pragma unroll
  for (int off = 32; off; off >>= 1) {
    #pragma unroll
    for (int e = 0; e < NE; e++) acc[e] += __shfl_xor(acc[e], off);
  }
  if (lane == 0) {
    int b0 = 0; double v0 = acc[0];
    #pragma unroll
    for (int e = 1; e < NE; e++) { if (acc[e] > v0) { v0 = acc[e]; b0 = e; } }
    int b1 = -1; double v1 = -1e300;
    #pragma unroll
    for (int e = 0; e < NE; e++) { if (e != b0 && acc[e] > v1) { v1 = acc[e]; b1 = e; } }
    double ex = exp(v1 - v0);
    te[n * 2] = b0; te[n * 2 + 1] = b1;
    tw[n * 2] = (float)(1.0 / (1.0 + ex));
    tw[n * 2 + 1] = (float)(ex / (1.0 + ex));
  }
}

// single-block deterministic dispatch build: counts, padded offs, perm, wgt,
// slotmap. Zero global atomics.
__global__ __launch_bounds__(256) void k_build(
    const int* __restrict__ te, const float* __restrict__ tw,
    int* __restrict__ counts, int* __restrict__ offs,
    int* __restrict__ perm, float* __restrict__ wgt, int* __restrict__ slotmap) {
  __shared__ int cnt[256][NE];
  __shared__ int pb[NE];
  int t = threadIdx.x;
  int ebuf[16];
  int lc[NE];
  #pragma unroll
  for (int e = 0; e < NE; e++) lc[e] = 0;
  #pragma unroll
  for (int i = 0; i < 16; i++) {
    int ei = te[t * 16 + i];
    ebuf[i] = ei;
    #pragma unroll
    for (int e = 0; e < NE; e++) lc[e] += (ei == e) ? 1 : 0;
  }
  #pragma unroll
  for (int e = 0; e < NE; e++) cnt[t][e] = lc[e];
  __syncthreads();
  if (t < NE) {  // exclusive prefix over threads for expert t
    int run = 0;
    for (int i = 0; i < 256; i++) { int v = cnt[i][t]; cnt[i][t] = run; run += v; }
    counts[t] = run;
  }
  __syncthreads();
  if (t == 0) {
    int off = 0;
    #pragma unroll
    for (int e = 0; e < NE; e++) {
      pb[e] = off; offs[e] = off;
      off += ((counts[e] + 127) >> 7) << 7;
    }
    offs[NE] = off;
  }
  for (int i = t; i < ACT_R_ROWS; i += 256) { perm[i] = 0; wgt[i] = 0.f; }
  __syncthreads();
  int run2[NE];
  #pragma unroll
  for (int e = 0; e < NE; e++) run2[e] = cnt[t][e];
  #pragma unroll
  for (int i = 0; i < 16; i++) {
    int ei = ebuf[i];
    int idx = 0;
    #pragma unroll
    for (int e = 0; e < NE; e++) {
      if (ei == e) idx = pb[e] + run2[e];
      run2[e] += (ei == e) ? 1 : 0;
    }
    perm[idx] = (t * 16 + i) >> 1;
    wgt[idx] = tw[t * 16 + i];
    slotmap[t * 16 + i] = idx;
  }
}

// ---------------- fused gate+up+SwiGLU GEMM, counted-vmcnt depth-2 ----------------
// C tile 128 rows x 64 cols. Group g = (by,z): g<16 shared; else routed e.
// Grid 1-D 1280 = 80 groups x 16 bx, XCD-swizzled (group -> one XCD).
__global__ __launch_bounds__(256, 2) void k_gu(
    const u16* __restrict__ xbf, const u16* __restrict__ WgT, const u16* __restrict__ WuT,
    const u16* __restrict__ sWgT, const u16* __restrict__ sWuT,
    u16* __restrict__ act_s, u16* __restrict__ act_r,
    const int* __restrict__ perm, const int* __restrict__ counts,
    const int* __restrict__ offs) {
  int lin = blockIdx.x;
  int xcd = lin & 7, jj = lin >> 3;
  int g = xcd + 8 * (jj % 10);   // 80 groups
  int bx = jj / 10;              // 16 row tiles
  const u16 *Bg, *Bu;
  u16* act;
  int Nout, cnt, rowBase, by;
  bool gather;
  if (g < 16) {
    gather = false; by = g;
    cnt = NTOK; rowBase = bx * 128;
    Bg = sWgT + (size_t)by * 64 * H;
    Bu = sWuT + (size_t)by * 64 * H;
    act = act_s; Nout = MS;
  } else {
    gather = true;
    int e = (g - 16) >> 3; by = (g - 16) & 7;
    cnt = counts[e];
    if (bx * 128 >= cnt) return;
    rowBase = offs[e] + bx * 128;
    Bg = WgT + ((size_t)e * MDIM + (size_t)by * 64) * H;
    Bu = WuT + ((size_t)e * MDIM + (size_t)by * 64) * H;
    act = act_r; Nout = MDIM;
  }

  __shared__ char lds[2][32768];  // A:0..16K, Bg:16K..24K, Bu:24K..32K

  int tid = threadIdx.x;
  int wave = tid >> 6, lane = tid & 63;
  int wr = wave >> 1, wc = wave & 1;
  int la = lane & 15, ks = lane >> 4;

  // staging sources (pre-swizzled chunk; rule #21 both-sides)
  int rIn = tid >> 3;
  int csrc = ((tid & 7) << 4) ^ ((rIn & 7) << 4);
  const char* srcA[4];
  const char* srcBg[2];
  const char* srcBu[2];
  #pragma unroll
  for (int j = 0; j < 4; j++) {
    int row = j * 32 + rIn;
    int tok = gather ? perm[rowBase + row] : (rowBase + row);
    srcA[j] = (const char*)xbf + (size_t)tok * H * 2 + csrc;
  }
  #pragma unroll
  for (int j = 0; j < 2; j++) {
    int row = j * 32 + rIn;
    srcBg[j] = (const char*)Bg + (size_t)row * H * 2 + csrc;
    srcBu[j] = (const char*)Bu + (size_t)row * H * 2 + csrc;
  }

  // fragment read offsets (swizzled), relative to buffer base
  int offA[4][2], offB[2][2];
  #pragma unroll
  for (int m = 0; m < 4; m++) {
    int arow = wr * 64 + m * 16 + la;
    #pragma unroll
    for (int kk = 0; kk < 2; kk++) {
      int c = kk * 64 + ks * 16;
      offA[m][kk] = arow * 128 + (c ^ ((arow & 7) << 4));
    }
  }
  #pragma unroll
  for (int n = 0; n < 2; n++) {
    int brow = wc * 32 + n * 16 + la;
    #pragma unroll
    for (int kk = 0; kk < 2; kk++) {
      int c = kk * 64 + ks * 16;
      offB[n][kk] = brow * 128 + (c ^ ((brow & 7) << 4));
    }
  }

  f32x4 zero4 = {0.f, 0.f, 0.f, 0.f};
  f32x4 gacc[4][2], uacc[4][2];
  #pragma unroll
  for (int m = 0; m < 4; m++)
    #pragma unroll
    for (int n = 0; n < 2; n++) { gacc[m][n] = zero4; uacc[m][n] = zero4; }

  auto STAGE = [&](int p, int k0) {
    char* b = lds[p];
    #pragma unroll
    for (int j = 0; j < 4; j++)
      gload16(srcA[j] + k0, b + j * 4096 + wave * 1024);
    #pragma unroll
    for (int j = 0; j < 2; j++) {
      gload16(srcBg[j] + k0, b + 16384 + j * 4096 + wave * 1024);
      gload16(srcBu[j] + k0, b + 24576 + j * 4096 + wave * 1024);
    }
  };

  const int NT = H / 64;  // 32
  STAGE(0, 0);
  STAGE(1, 128);
  asm volatile("s_waitcnt vmcnt(8)" ::: "memory");
  __builtin_amdgcn_sched_barrier(0);
  __builtin_amdgcn_s_barrier();

  for (int t = 0; t < NT; ++t) {
    int p = t & 1;
    const char* A = lds[p];
    const char* G = lds[p] + 16384;
    const char* U = lds[p] + 24576;
    s16x8 af[2][4], gf[2][2], uf[2][2];
    #pragma unroll
    for (int kk = 0; kk < 2; kk++) {
      #pragma unroll
      for (int m = 0; m < 4; m++) af[kk][m] = *(const s16x8*)(A + offA[m][kk]);
      #pragma unroll
      for (int n = 0; n < 2; n++) {
        gf[kk][n] = *(const s16x8*)(G + offB[n][kk]);
        uf[kk][n] = *(const s16x8*)(U + offB[n][kk]);
      }
    }
    asm volatile("s_waitcnt lgkmcnt(0)" ::: "memory");
    __builtin_amdgcn_sched_barrier(0);
    __builtin_amdgcn_s_barrier();           // all waves done reading buf p
    if (t + 2 < NT) STAGE(p, (t + 2) * 128);  // overwrite buf p (reads retired)
    __builtin_amdgcn_sched_barrier(0);
    #pragma unroll
    for (int kk = 0; kk < 2; kk++) {
      #pragma unroll
      for (int m = 0; m < 4; m++) {
        #pragma unroll
        for (int n = 0; n < 2; n++) {
          gacc[m][n] = mfma16(af[kk][m], gf[kk][n], gacc[m][n]);
          uacc[m][n] = mfma16(af[kk][m], uf[kk][n], uacc[m][n]);
        }
      }
    }
    if (t + 2 < NT) { asm volatile("s_waitcnt vmcnt(8)" ::: "memory"); }
    else            { asm volatile("s_waitcnt vmcnt(0)" ::: "memory"); }
    __builtin_amdgcn_sched_barrier(0);
    __builtin_amdgcn_s_barrier();           // publish buf p^1 (tile t+1)
  }

  #pragma unroll
  for (int m = 0; m < 4; m++) {
    #pragma unroll
    for (int n = 0; n < 2; n++) {
      #pragma unroll
      for (int r = 0; r < 4; r++) {
        int lr = wr * 64 + m * 16 + ks * 4 + r;
        int col = by * 64 + wc * 32 + n * 16 + la;
        float gg = gacc[m][n][r], uu = uacc[m][n][r];
        float a = gg / (1.0f + __expf(-gg)) * uu;
        if (gather && (bx * 128 + lr) >= cnt) a = 0.0f;
        act[(size_t)(rowBase + lr) * Nout + col] = f2bf(a);
      }
    }
  }
}

// ---------------- merged down GEMM (shared + routed), atomic-free ----------------
// C tile 128 rows x 64 cols. Groups: g<32 shared (by=g); else routed e,by.
// Shared: dense fp32 store into y. Routed: weighted bf16 store into rdown[slot].
__global__ __launch_bounds__(256, 3) void k_down2(
    const u16* __restrict__ act_s, const u16* __restrict__ act_r,
    const u16* __restrict__ sWdT, const u16* __restrict__ WdT,
    float* __restrict__ y, u16* __restrict__ rdown,
    const float* __restrict__ wgt,
    const int* __restrict__ counts, const int* __restrict__ offs) {
  int lin = blockIdx.x;
  int xcd = lin & 7, jj = lin >> 3;
  int g = xcd + 8 * (jj % 36);   // 288 groups
  int bx = jj / 36;              // 16 row tiles
  const u16 *A, *B;
  int KD, NT, cnt, rowBase, by;
  bool routed;
  if (g < 32) {
    routed = false; by = g;
    KD = MS; NT = MS / 64;
    cnt = NTOK; rowBase = bx * 128;
    A = act_s + (size_t)rowBase * MS;
    B = sWdT + (size_t)by * 64 * MS;
  } else {
    routed = true;
    int e = (g - 32) >> 5; by = (g - 32) & 31;
    KD = MDIM; NT = MDIM / 64;
    cnt = counts[e];
    if (bx * 128 >= cnt) return;
    rowBase = offs[e] + bx * 128;
    A = act_r + (size_t)rowBase * MDIM;
    B = WdT + ((size_t)e * H + (size_t)by * 64) * MDIM;
  }

  __shared__ char lds[2][24576];  // A:0..16K, B:16K..24K

  int tid = threadIdx.x;
  int wave = tid >> 6, lane = tid & 63;
  int wr = wave >> 1, wc = wave & 1;
  int la = lane & 15, ks = lane >> 4;

  int rIn = tid >> 3;
  int csrc = ((tid & 7) << 4) ^ ((rIn & 7) << 4);
  const char* srcA[4];
  const char* srcB[2];
  #pragma unroll
  for (int j = 0; j < 4; j++) {
    int row = j * 32 + rIn;
    srcA[j] = (const char*)A + (size_t)row * KD * 2 + csrc;
  }
  #pragma unroll
  for (int j = 0; j < 2; j++) {
    int row = j * 32 + rIn;
    srcB[j] = (const char*)B + (size_t)row * KD * 2 + csrc;
  }

  int offA[4][2], offB[2][2];
  #pragma unroll
  for (int m = 0; m < 4; m++) {
    int arow = wr * 64 + m * 16 + la;
    #pragma unroll
    for (int kk = 0; kk < 2; kk++) {
      int c = kk * 64 + ks * 16;
      offA[m][kk] = arow * 128 + (c ^ ((arow & 7) << 4));
    }
  }
  #pragma unroll
  for (int n = 0; n < 2; n++) {
    int brow = wc * 32 + n * 16 + la;
    #pragma unroll
    for (int kk = 0; kk < 2; kk++) {
      int c = kk * 64 + ks * 16;
      offB[n][kk] = brow * 128 + (c ^ ((brow & 7) << 4));
    }
  }

  f32x4 zero4 = {0.f, 0.f, 0.f, 0.f};
  f32x4 acc[4][2];
  #pragma unroll
  for (int m = 0; m < 4; m++)
    #pragma unroll
    for (int n = 0; n < 2; n++) acc[m][n] = zero4;

  auto STAGE = [&](int p, int k0) {
    char* b = lds[p];
    #pragma unroll
    for (int j = 0; j < 4; j++)
      gload16(srcA[j] + k0, b + j * 4096 + wave * 1024);
    #pragma unroll
    for (int j = 0; j < 2; j++)
      gload16(srcB[j] + k0, b + 16384 + j * 4096 + wave * 1024);
  };

  STAGE(0, 0);
  STAGE(1, 128);
  asm volatile("s_waitcnt vmcnt(6)" ::: "memory");
  __builtin_amdgcn_sched_barrier(0);
  __builtin_amdgcn_s_barrier();

  for (int t = 0; t < NT; ++t) {
    int p = t & 1;
    const char* Ab = lds[p];
    const char* Bb = lds[p] + 16384;
    s16x8 af[2][4], bf[2][2];
    #pragma unroll
    for (int kk = 0; kk < 2; kk++) {
      #pragma unroll
      for (int m = 0; m < 4; m++) af[kk][m] = *(const s16x8*)(Ab + offA[m][kk]);
      #pragma unroll
      for (int n = 0; n < 2; n++) bf[kk][n] = *(const s16x8*)(Bb + offB[n][kk]);
    }
    asm volatile("s_waitcnt lgkmcnt(0)" ::: "memory");
    __builtin_amdgcn_sched_barrier(0);
    __builtin_amdgcn_s_barrier();
    if (t + 2 < NT) STAGE(p, (t + 2) * 128);
    __builtin_amdgcn_sched_barrier(0);
    #pragma unroll
    for (int kk = 0; kk < 2; kk++) {
      #pragma unroll
      for (int m = 0; m < 4; m++)
        #pragma unroll
        for (int n = 0; n < 2; n++) acc[m][n] = mfma16(af[kk][m], bf[kk][n], acc[m][n]);
    }
    if (t + 2 < NT) { asm volatile("s_waitcnt vmcnt(6)" ::: "memory"); }
    else            { asm volatile("s_waitcnt vmcnt(0)" ::: "memory"); }
    __builtin_amdgcn_sched_barrier(0);
    __builtin_amdgcn_s_barrier();
  }

  #pragma unroll
  for (int m = 0; m < 4; m++) {
    #pragma unroll
    for (int n = 0; n < 2; n++) {
      #pragma unroll
      for (int r = 0; r < 4; r++) {
        int lr = wr * 64 + m * 16 + ks * 4 + r;
        int col = by * 64 + wc * 32 + n * 16 + la;
        float v = acc[m][n][r];
        if (routed) {
          if (bx * 128 + lr < cnt) {
            int si = rowBase + lr;
            rdown[(size_t)si * H + col] = f2bf(wgt[si] * v);
          }
        } else {
          y[(size_t)(rowBase + lr) * H + col] = v;
        }
      }
    }
  }
}

// ---------------- combine: y[tok] += rdown[slot0] + rdown[slot1] ----------------
__global__ __launch_bounds__(256) void k_combine(float* __restrict__ y,
                                                 const u16* __restrict__ rdown,
                                                 const int* __restrict__ slotmap) {
  int n = blockIdx.x;
  int s0 = slotmap[n * 2], s1 = slotmap[n * 2 + 1];
  const s16x8* r0 = (const s16x8*)(rdown + (size_t)s0 * H);
  const s16x8* r1 = (const s16x8*)(rdown + (size_t)s1 * H);
  f32x4* yp = (f32x4*)(y + (size_t)n * H);
  int t = threadIdx.x;
  s16x8 a = r0[t], b = r1[t];
  f32x4 y0 = yp[2 * t], y1 = yp[2 * t + 1];
  #pragma unroll
  for (int j = 0; j < 4; j++) {
    y0[j] += bf2f((u16)a[j]) + bf2f((u16)b[j]);
    y1[j] += bf2f((u16)a[4 + j]) + bf2f((u16)b[4 + j]);
  }
  yp[2 * t] = y0;
  yp[2 * t + 1] = y1;
}

// ---------------- host launch ----------------

extern "C" void kernel_launch(void* const* d_in, const int* in_sizes, int n_in,
                              void* d_out, int out_size, void* d_ws, size_t ws_size,
                              hipStream_t stream) {
  const float* x   = (const float*)d_in[0];
  const float* gw  = (const float*)d_in[1];
  const float* Wg  = (const float*)d_in[2];
  const float* Wu  = (const float*)d_in[3];
  const float* Wd  = (const float*)d_in[4];
  const float* sWg = (const float*)d_in[5];
  const float* sWu = (const float*)d_in[6];
  const float* sWd = (const float*)d_in[7];
  float* y = (float*)d_out;

  char* w = (char*)d_ws;
  auto alloc = [&](size_t bytes) {
    char* p = w;
    w += (bytes + 255) & ~(size_t)255;
    return p;
  };
  u16* xbf   = (u16*)alloc((size_t)NTOK * H * 2);
  u16* WgT   = (u16*)alloc((size_t)NE * MDIM * H * 2);
  u16* WuT   = (u16*)alloc((size_t)NE * MDIM * H * 2);
  u16* WdT   = (u16*)alloc((size_t)NE * H * MDIM * 2);
  u16* sWgT  = (u16*)alloc((size_t)MS * H * 2);
  u16* sWuT  = (u16*)alloc((size_t)MS * H * 2);
  u16* sWdT  = (u16*)alloc((size_t)H * MS * 2);
  u16* act_s = (u16*)alloc((size_t)NTOK * MS * 2);
  u16* act_r = (u16*)alloc((size_t)ACT_R_ROWS * MDIM * 2);
  u16* rdown = (u16*)alloc((size_t)ACT_R_ROWS * H * 2);
  int*   te      = (int*)alloc((size_t)NTOK * 2 * 4);
  float* tw      = (float*)alloc((size_t)NTOK * 2 * 4);
  int*   counts  = (int*)alloc(64);
  int*   offs    = (int*)alloc(64);
  int*   perm    = (int*)alloc((size_t)ACT_R_ROWS * 4);
  float* wgt     = (float*)alloc((size_t)ACT_R_ROWS * 4);
  int*   slotmap = (int*)alloc((size_t)NTOK * 2 * 4);

  // atomic-free routing
  k_logits<<<NTOK / 4, 256, 0, stream>>>(x, gw, te, tw);
  k_build<<<1, 256, 0, stream>>>(te, tw, counts, offs, perm, wgt, slotmap);

  int n8 = NTOK * H / 8;
  k_cvt<<<(n8 + 255) / 256, 256, 0, stream>>>(x, xbf, n8);
  // all weight transposes in one dispatch
  k_prep<<<7680, 256, 0, stream>>>(Wg, Wu, Wd, sWg, sWu, sWd,
                                   WgT, WuT, WdT, sWgT, sWuT, sWdT);

  // merged shared (g<16) + routed gate/up, fused SwiGLU, counted-vmcnt pipeline
  k_gu<<<80 * 16, 256, 0, stream>>>(
      xbf, WgT, WuT, sWgT, sWuT, act_s, act_r, perm, counts, offs);

  // merged down: shared -> dense y stores; routed -> weighted bf16 rdown stores
  k_down2<<<288 * 16, 256, 0, stream>>>(
      act_s, act_r, sWdT, WdT, y, rdown, wgt, counts, offs);

  // per-token combine of the two routed contributions
  k_combine<<<NTOK, 256, 0, stream>>>(y, rdown, slotmap);
}